// Round 10
// baseline (155.405 us; speedup 1.0000x reference)
//
#include <hip/hip_runtime.h>

typedef unsigned short u16;
typedef unsigned int   u32;
typedef __attribute__((ext_vector_type(8))) short short8;   // 8 x bf16 (4 VGPRs)
typedef __attribute__((ext_vector_type(16))) float f32x16;

#define MFMA32(a, b, c) __builtin_amdgcn_mfma_f32_32x32x16_bf16(a, b, c, 0, 0, 0)

constexpr int Lv = 2048, Hv = 8, Ev = 64, HE = Hv * Ev; // HE=512
constexpr float QSCALE = 0.18033688011112042f;          // 0.125 * log2(e)
constexpr size_t WSV_OFF = 32u * 64u * 2048u;           // u16 offset of V images
// ws layout: K images [bh*64+tg]*2048 u16, then V images. 16 MB total.
#define WS_NEED ((size_t)16777216)

__device__ __forceinline__ float bf2f(u16 u) {
    u32 x = ((u32)u) << 16;
    return __builtin_bit_cast(float, x);
}
__device__ __forceinline__ u16 f2bf(float f) {   // RNE, finite inputs
    u32 x = __builtin_bit_cast(u32, f);
    u32 r = ((x >> 16) & 1u) + 0x7fffu;
    return (u16)((x + r) >> 16);
}
__device__ __forceinline__ u32 pkbf(float a, float b) {
#if __has_builtin(__builtin_amdgcn_cvt_pk_bf16_f32)
    typedef __attribute__((ext_vector_type(2))) __bf16 bf16x2;
    bf16x2 v = __builtin_amdgcn_cvt_pk_bf16_f32(a, b);
    return __builtin_bit_cast(u32, v);
#else
    return (u32)f2bf(a) | ((u32)f2bf(b) << 16);
#endif
}
__device__ __forceinline__ float fexp2(float x) {
#if __has_builtin(__builtin_amdgcn_exp2f)
    return __builtin_amdgcn_exp2f(x);
#else
    return exp2f(x);
#endif
}

// Runtime dtype sniff (validated rounds 0-9: fp32 inputs detected correctly).
__device__ __forceinline__ int detect_isbf16(const u32* q32, int lane) {
    u32 w0 = q32[2 * lane];
    u32 w1 = q32[2 * lane + 1];
    u16 uu[4] = { (u16)(w0 & 0xffff), (u16)(w0 >> 16),
                  (u16)(w1 & 0xffff), (u16)(w1 >> 16) };
    int p = 0, z = 0;
#pragma unroll
    for (int j = 0; j < 4; ++j) {
        u16 mgn = (u16)(uu[j] & 0x7fff);
        int ex  = mgn >> 7;
        bool zero = (mgn == 0);
        bool pl   = zero || (ex >= 115 && ex <= 132);
        p += pl ? 1 : 0;
        if ((j & 1) == 0) z += zero ? 1 : 0;
    }
    int acc = p | (z << 16);
#pragma unroll
    for (int o = 1; o < 64; o <<= 1) acc += __shfl_xor(acc, o);
    int ps = acc & 0xffff, zs = acc >> 16;
    if (zs >= 100) return 0;
    return (ps >= 240) ? 1 : 0;
}

__device__ __forceinline__ short8 cvt8s(const float* p, float s) {
    float4 a = *(const float4*)p, b4 = *(const float4*)(p + 4);
    u32 r[4] = { pkbf(a.x * s, a.y * s), pkbf(a.z * s, a.w * s),
                 pkbf(b4.x * s, b4.y * s), pkbf(b4.z * s, b4.w * s) };
    return *(short8*)r;
}

__device__ __forceinline__ f32x16 zv16() {
    f32x16 z;
#pragma unroll
    for (int r = 0; r < 16; ++r) z[r] = 0.f;
    return z;
}

// Exchange a.hi-lanes <-> b.lo-lanes (v_permlane32_swap_b32 semantics).
__device__ __forceinline__ void plswap(u32& a, u32& b) {
#if __has_builtin(__builtin_amdgcn_permlane32_swap)
    auto r = __builtin_amdgcn_permlane32_swap(a, b, false, false);
    a = r[0]; b = r[1];
#else
    int lane = (int)(threadIdx.x & 63);
    u32 ax = (u32)__shfl_xor((int)a, 32);
    u32 bx = (u32)__shfl_xor((int)b, 32);
    bool hi = lane >= 32;
    u32 na = hi ? bx : a;
    u32 nb = hi ? b  : ax;
    a = na; b = nb;
#endif
}

// ---------------------------------------------------------------------------
// Convert kernel: K/V -> bf16 images in ws, pre-swizzled into the EXACT byte
// layout the attn kernel's wave-private LDS tiles use (m173 pattern), so
// attn staging is a flat uint4 copy (no cvt, no swizzle math).
// K image (per bh,tile: 2048 u16 = 32 keys x 64 e):
//   addr a: key=a>>6, slotf=(a&63)>>3, j=a&7, e=((slotf^(key&7))<<3)+j
// V image (2048 u16 = 64 e x 32 keys, transposed):
//   addr a: e=a>>5, slotf=(a&31)>>3, j=a&7, key=((slotf^((e+(e>>3))&3))<<3)+j
// ---------------------------------------------------------------------------
template <int ISBF>
__device__ __forceinline__ void convert_impl(const void* kin, const void* vin,
                                             u16* __restrict__ ws) {
    const int blk = blockIdx.x;        // bh*64 + tg
    const int bh  = blk >> 6, tg = blk & 63;
    const int b   = bh >> 3,  h  = bh & 7;
    const size_t inb = (size_t)b * Lv * HE + h * Ev;
    u16* kimg = ws + (size_t)blk * 2048;
    u16* vimg = ws + WSV_OFF + (size_t)blk * 2048;
    const int t = threadIdx.x;
#pragma unroll
    for (int r = 0; r < 4; ++r) {
        const int i = t + 256 * r;     // u32 index 0..1023
        const int a = 2 * i;
        {   // K
            int key = a >> 6;
            int slotf = (a & 63) >> 3, j0 = a & 7;
            int e0 = ((slotf ^ (key & 7)) << 3) + j0;
            size_t s = inb + (size_t)(tg * 32 + key) * HE + e0;
            u32 val;
            if (ISBF) { const u16* p = (const u16*)kin + s; val = (u32)p[0] | ((u32)p[1] << 16); }
            else      { const float* p = (const float*)kin + s; val = pkbf(p[0], p[1]); }
            *(u32*)&kimg[a] = val;
        }
        {   // V (transposed: u32 packs keys {k0,k0+1} at same e)
            int e = a >> 5;
            int slotf = (a & 31) >> 3, j0 = a & 7;
            int k0 = ((slotf ^ ((e + (e >> 3)) & 3)) << 3) + j0;
            size_t s0 = inb + (size_t)(tg * 32 + k0) * HE + e;
            u32 val;
            if (ISBF) { const u16* p = (const u16*)vin; val = (u32)p[s0] | ((u32)p[s0 + HE] << 16); }
            else      { const float* p = (const float*)vin; val = pkbf(p[s0], p[s0 + HE]); }
            *(u32*)&vimg[a] = val;
        }
    }
}

__global__ __launch_bounds__(256) void convert_kernel(
    const void* __restrict__ qv, const void* __restrict__ kv,
    const void* __restrict__ vv, u16* __restrict__ ws)
{
    const int isbf = detect_isbf16((const u32*)qv, threadIdx.x & 63);
    if (isbf) convert_impl<1>(kv, vv, ws);
    else      convert_impl<0>(kv, vv, ws);
}

// ---------------------------------------------------------------------------
// Fused full attention + l=0 local blend.  Round-10: BARRIER-FREE K-loop.
// 512 blocks x 512 thr. Wave w = (qg=w&3: 32 queries) x (g=w>>2: 1024 keys).
// Each wave owns a PRIVATE 8 KB LDS slice (K 4KB + V 4KB, 32-key tiles,
// single-buffered: in-order LDS pipe makes store(kt+1)-after-read(kt) safe
// within a wave). NO s_barrier in the 32-iteration loop -> waves drift; the
// phase convoy (VALU 50% + LDS 48% + MFMA 18%, none saturated, R3-R8) is
// dissolved by cross-wave TLP. 4 waves/SIMD (2 blocks/CU, 128 KB LDS).
// WS=1: staging = flat uint4 copies from pre-swizzled bf16 images in ws.
// WS=0 fallback: direct fp32/bf16 staging with in-kernel cvt+swizzle.
// Split-K halves combined through LDS at the end (exact, unnormalized).
// ---------------------------------------------------------------------------
template <int ISBF, int WS>
__device__ __forceinline__ void attn_impl(
    const void* __restrict__ qv, const void* __restrict__ kv,
    const void* __restrict__ vv, const void* __restrict__ alphav,
    void* __restrict__ outv, const u16* __restrict__ ws, u16* SMEM)
{
    const int tid  = threadIdx.x;       // 0..511
    const int w    = tid >> 6;          // wave 0..7
    const int lane = tid & 63;
    const int l31  = lane & 31;
    const int hi   = lane >> 5;
    const int qg   = w & 3;             // query sub-block (32 rows)
    const int g    = w >> 2;            // key-half group (1024 keys)

    // XCD-aware mapping: xcd = fid&7 handles bh in {4*xcd .. 4*xcd+3}.
    const int fid = blockIdx.x;         // 0..511
    const int bh  = (fid & 7) * 4 + ((fid >> 3) & 3);
    const int rb  = fid >> 5;           // 0..15
    const int b   = bh >> 3, h = bh & 7;
    const int row0 = rb * 128;

    const size_t bhoff = (size_t)b * Lv * HE + h * Ev;
    const u16*   q16 = (const u16*)qv + bhoff;
    const u16*   k16 = (const u16*)kv + bhoff;
    const u16*   v16 = (const u16*)vv + bhoff;
    const float* q32 = (const float*)qv + bhoff;
    const float* k32 = (const float*)kv + bhoff;
    const float* v32 = (const float*)vv + bhoff;

    // wave-private LDS slice: K tile [32 key][64 e] + V tile [64 e][32 key]
    u16* ldsK = SMEM + w * 4096;
    u16* ldsV = ldsK + 2048;

    // Q fragments (pre-scaled). qf[c][j] = Qs[row0+qg*32+l31][16c+8hi+j].
    short8 qf[4];
    {
        size_t ro = (size_t)(row0 + qg * 32 + l31) * HE + hi * 8;
        if (ISBF) {
#pragma unroll
            for (int c = 0; c < 4; ++c) {
                short8 t = *(const short8*)(q16 + ro + 16 * c);
#pragma unroll
                for (int j = 0; j < 8; ++j)
                    qf[c][j] = (short)f2bf(bf2f((u16)t[j]) * QSCALE);
            }
        } else {
#pragma unroll
            for (int c = 0; c < 4; ++c) qf[c] = cvt8s(q32 + ro + 16 * c, QSCALE);
        }
    }

    f32x16 O[2];
    O[0] = zv16(); O[1] = zv16();
    float psum = 0.f;

    // image bases (WS=1): tile tg = g*32 + kt
    const u16* kimg0 = ws + ((size_t)bh * 64 + g * 32) * 2048;
    const u16* vimg0 = ws + WSV_OFF + ((size_t)bh * 64 + g * 32) * 2048;
    const size_t keybase = (size_t)g * 1024;     // WS=0 global key offset

    // WS=0 staging lane mapping
    const int k0l = lane >> 3;          // K: key = c*8 + k0l ; V: kp = k0l
    const int kj  = lane & 7;
    const int e0K = ((kj ^ k0l) << 3);  // K source e-offset (key&7 == k0l)
    const int eoV = kj * 8;             // V e-octet

    // prefetch registers (single 16-reg set per batch, reused sequentially)
    uint4  kr0, kr1, kr2, kr3;          // WS=1 image chunks (also reused for V)
    float4 fpa, fpb, fpc, fpd;          // WS=0 fp32 batch
    uint4  upa, upb;                    // WS=0 bf16 batch

    // ---------------- staging macros ----------------
#define LK1(KT) do { const u16* ib_ = kimg0 + (size_t)(KT) * 2048 + lane * 8;  \
        kr0 = *(const uint4*)ib_;        kr1 = *(const uint4*)(ib_ + 512);     \
        kr2 = *(const uint4*)(ib_ + 1024); kr3 = *(const uint4*)(ib_ + 1536); } while (0)
#define SK1() do { *(uint4*)&ldsK[lane * 8] = kr0;                             \
        *(uint4*)&ldsK[512 + lane * 8] = kr1;                                  \
        *(uint4*)&ldsK[1024 + lane * 8] = kr2;                                 \
        *(uint4*)&ldsK[1536 + lane * 8] = kr3; } while (0)
#define LV1(KT) do { const u16* ib_ = vimg0 + (size_t)(KT) * 2048 + lane * 8;  \
        kr0 = *(const uint4*)ib_;        kr1 = *(const uint4*)(ib_ + 512);     \
        kr2 = *(const uint4*)(ib_ + 1024); kr3 = *(const uint4*)(ib_ + 1536); } while (0)
#define SV1() do { *(uint4*)&ldsV[lane * 8] = kr0;                             \
        *(uint4*)&ldsV[512 + lane * 8] = kr1;                                  \
        *(uint4*)&ldsV[1024 + lane * 8] = kr2;                                 \
        *(uint4*)&ldsV[1536 + lane * 8] = kr3; } while (0)

    // WS=0: K half CH (0: c=0,1 ; 1: c=2,3)
#define LK0(KT, CH) do {                                                       \
        size_t tb_ = (keybase + (size_t)(KT) * 32) * HE;                       \
        int key_ = (CH) * 16 + k0l;                                            \
        if (ISBF) {                                                            \
            const u16* p_ = k16 + tb_ + (size_t)key_ * HE + e0K;               \
            upa = *(const uint4*)p_;                                           \
            upb = *(const uint4*)(p_ + 8 * HE);                                \
        } else {                                                               \
            const float* p_ = k32 + tb_ + (size_t)key_ * HE + e0K;             \
            fpa = *(const float4*)p_;            fpb = *(const float4*)(p_ + 4);\
            fpc = *(const float4*)(p_ + 8 * HE); fpd = *(const float4*)(p_ + 8 * HE + 4);\
        }                                                                      \
    } while (0)
#define SK0(CH) do {                                                           \
        if (ISBF) {                                                            \
            *(uint4*)&ldsK[((CH)*2    ) * 512 + lane * 8] = upa;               \
            *(uint4*)&ldsK[((CH)*2 + 1) * 512 + lane * 8] = upb;               \
        } else {                                                               \
            u32 t0_[4] = { pkbf(fpa.x, fpa.y), pkbf(fpa.z, fpa.w),             \
                           pkbf(fpb.x, fpb.y), pkbf(fpb.z, fpb.w) };           \
            u32 t1_[4] = { pkbf(fpc.x, fpc.y), pkbf(fpc.z, fpc.w),             \
                           pkbf(fpd.x, fpd.y), pkbf(fpd.z, fpd.w) };           \
            *(uint4*)&ldsK[((CH)*2    ) * 512 + lane * 8] = *(uint4*)t0_;      \
            *(uint4*)&ldsK[((CH)*2 + 1) * 512 + lane * 8] = *(uint4*)t1_;      \
        }                                                                      \
    } while (0)
    // Wait: LK0 half CH covers keys {CH*16 + k0l, CH*16 + k0l + 8} -> those
    // are c = 2*CH and 2*CH+1 rows: key_ = c*8+k0l requires key stride 8*HE ✓
    // and SK0 writes chunks c=2CH, 2CH+1 at lane*8 ✓ (e0K independent of c).

    // WS=0: V half VH (0: keys 0..15 ; 1: keys 16..31); lane: keys 2kp,2kp+1
#define LV0(KT, VH) do {                                                       \
        size_t tb_ = (keybase + (size_t)(KT) * 32 + (VH) * 16 + 2 * k0l) * HE; \
        if (ISBF) {                                                            \
            const u16* p_ = v16 + tb_ + eoV;                                   \
            upa = *(const uint4*)p_;                                           \
            upb = *(const uint4*)(p_ + HE);                                    \
        } else {                                                               \
            const float* p_ = v32 + tb_ + eoV;                                 \
            fpa = *(const float4*)p_;       fpb = *(const float4*)(p_ + 4);    \
            fpc = *(const float4*)(p_ + HE); fpd = *(const float4*)(p_ + HE + 4);\
        }                                                                      \
    } while (0)
#define SV0(VH) do {                                                           \
        int s_ = (k0l >> 2) + (VH) * 2;                                        \
        if (ISBF) {                                                            \
            const u16* a0_ = (const u16*)&upa;                                 \
            const u16* a1_ = (const u16*)&upb;                                 \
            _Pragma("unroll")                                                  \
            for (int j = 0; j < 8; ++j) {                                      \
                int e_ = eoV + j;                                              \
                int sl_ = s_ ^ ((e_ + (e_ >> 3)) & 3);                         \
                *(u32*)&ldsV[e_ * 32 + sl_ * 8 + ((2 * k0l) & 7)] =            \
                    (u32)a0_[j] | ((u32)a1_[j] << 16);                         \
            }                                                                  \
        } else {                                                               \
            float t0_[8] = {fpa.x, fpa.y, fpa.z, fpa.w, fpb.x, fpb.y, fpb.z, fpb.w};\
            float t1_[8] = {fpc.x, fpc.y, fpc.z, fpc.w, fpd.x, fpd.y, fpd.z, fpd.w};\
            _Pragma("unroll")                                                  \
            for (int j = 0; j < 8; ++j) {                                      \
                int e_ = eoV + j;                                              \
                int sl_ = s_ ^ ((e_ + (e_ >> 3)) & 3);                         \
                *(u32*)&ldsV[e_ * 32 + sl_ * 8 + ((2 * k0l) & 7)] =            \
                    pkbf(t0_[j], t1_[j]);                                      \
            }                                                                  \
        }                                                                      \
    } while (0)

    // ---------------- compute macros ----------------
    f32x16 St;
#define QK_() do {                                                             \
        St = zv16();                                                           \
        __builtin_amdgcn_s_setprio(1);                                         \
        _Pragma("unroll")                                                      \
        for (int c = 0; c < 4; ++c) {                                          \
            int sl = (2 * c + hi) ^ (l31 & 7);                                 \
            short8 kf = *(const short8*)&ldsK[l31 * 64 + sl * 8];              \
            St = MFMA32(kf, qf[c], St);                                        \
        }                                                                      \
        __builtin_amdgcn_s_setprio(0);                                         \
    } while (0)

    u32 c8[8];
#define SM_() do {                                                             \
        _Pragma("unroll")                                                      \
        for (int r = 0; r < 16; ++r) St[r] = fexp2(St[r]);                     \
        _Pragma("unroll")                                                      \
        for (int r = 0; r < 16; ++r) psum += St[r];                            \
        _Pragma("unroll")                                                      \
        for (int q = 0; q < 8; ++q) c8[q] = pkbf(St[2 * q], St[2 * q + 1]);    \
    } while (0)

#define PV_(T) do {                                                            \
        u32 a0 = c8[4 * (T) + 0], a1 = c8[4 * (T) + 1];                        \
        u32 a2 = c8[4 * (T) + 2], a3 = c8[4 * (T) + 3];                        \
        plswap(a0, a2);                                                        \
        plswap(a1, a3);                                                        \
        u32 pw_[4] = { a0, a1, a2, a3 };                                       \
        short8 pa = *(short8*)pw_;                                             \
        __builtin_amdgcn_s_setprio(1);                                         \
        _Pragma("unroll")                                                      \
        for (int et = 0; et < 2; ++et) {                                       \
            int e  = et * 32 + l31;                                            \
            int sl = (2 * (T) + hi) ^ ((e + (e >> 3)) & 3);                    \
            short8 vf = *(const short8*)&ldsV[e * 32 + sl * 8];                \
            O[et] = MFMA32(pa, vf, O[et]);                                     \
        }                                                                      \
        __builtin_amdgcn_s_setprio(0);                                         \
    } while (0)

    // ---------------- barrier-free K-loop ----------------
    if (WS) {
        LK1(0); SK1(); LV1(0); SV1();          // prologue: tile 0 resident
        for (int kt = 0; kt < 32; ++kt) {
            if (kt < 31) LK1(kt + 1);          // in flight across QK
            QK_();
            if (kt < 31) SK1();                // ldsK := tile kt+1 (QK done)
            SM_();
            if (kt < 31) LV1(kt + 1);          // in flight across PV
            PV_(0);
            PV_(1);
            if (kt < 31) SV1();                // ldsV := tile kt+1 (PV done)
        }
    } else {
        LK0(0, 0); SK0(0); LK0(0, 1); SK0(1);
        LV0(0, 0); SV0(0); LV0(0, 1); SV0(1);
        for (int kt = 0; kt < 32; ++kt) {
            if (kt < 31) LK0(kt + 1, 0);
            QK_();
            if (kt < 31) { SK0(0); LK0(kt + 1, 1); }
            SM_();
            if (kt < 31) { SK0(1); LV0(kt + 1, 0); }
            PV_(0);                             // reads V keys 0..15 of kt
            if (kt < 31) { SV0(0); LV0(kt + 1, 1); }
            PV_(1);                             // reads V keys 16..31 of kt
            if (kt < 31) SV0(1);
        }
    }
#undef LK1
#undef SK1
#undef LV1
#undef SV1
#undef LK0
#undef SK0
#undef LV0
#undef SV0
#undef QK_
#undef SM_
#undef PV_

    // ---- combine the two key-halves through LDS (exact, unnormalized) ----
    __syncthreads();                              // all waves done with tiles
    float pst = psum + __shfl_xor(psum, 32);      // row sum over this half
    float* cb = (float*)SMEM;                     // tiles dead; reuse as f32
    const int cbase = qg * 2368 + lane * 36;      // 36 f32 stride: 16B-aligned

    if (g == 1) {
        union { f32x16 v; float4 q4[4]; } u;
        u.v = O[0];
#pragma unroll
        for (int i = 0; i < 4; ++i) *(float4*)&cb[cbase + 4 * i] = u.q4[i];
        u.v = O[1];
#pragma unroll
        for (int i = 0; i < 4; ++i) *(float4*)&cb[cbase + 16 + 4 * i] = u.q4[i];
        cb[qg * 2368 + 2304 + lane] = pst;
    }

    // ---- l=0 local attention (wave 0 = qg0/g0 of rb==0 blocks) ----
    float locv[2] = {0.f, 0.f};
    float wgt = 0.f;
    const bool w0blk = (rb == 0) && (w == 0);
    if (w0blk) {
        const int e = lane;
        const size_t base = bhoff + e;
#define LDIN(p, i) (ISBF ? bf2f(((const u16*)(p))[i]) : ((const float*)(p))[i])
        float qe = LDIN(qv, base);
        float s[9];
#pragma unroll
        for (int j = 0; j < 9; ++j) {
            float prod = qe * LDIN(kv, base + (size_t)j * HE);
#pragma unroll
            for (int o = 1; o < 64; o <<= 1) prod += __shfl_xor(prod, o);
            s[j] = prod * 0.125f;
        }
        float mx = s[0];
#pragma unroll
        for (int j = 1; j < 9; ++j) mx = fmaxf(mx, s[j]);
        float we[9];
#pragma unroll
        for (int j = 0; j < 9; ++j) we[j] = expf(s[j] - mx);
        float denom = 9.f * we[0];
        float acc   = 9.f * we[0] * LDIN(vv, base);
#pragma unroll
        for (int j = 1; j < 9; ++j) {
            denom += we[j];
            acc   += we[j] * LDIN(vv, base + (size_t)j * HE);
        }
        float loc = acc / denom;

        float a;
        if (ISBF) {
            a = bf2f(((const u16*)alphav)[0]);
            if (!(a >= 0.0f && a <= 1.0f)) {
                float af = ((const float*)alphav)[0];
                if (af >= 0.0f && af <= 1.0f) a = af;
            }
        } else {
            a = ((const float*)alphav)[0];
            if (!(a >= 0.0f && a <= 1.0f)) {
                float ab = bf2f(((const u16*)alphav)[0]);
                if (ab >= 0.0f && ab <= 1.0f) a = ab;
            }
        }
        wgt = 1.f / (1.f + expf(-a));
#pragma unroll
        for (int et = 0; et < 2; ++et) locv[et] = __shfl(loc, et * 32 + l31);
#undef LDIN
    }

    __syncthreads();                              // partials visible
    if (g != 0) return;

    // ---- g==0 waves: add partner partials, normalize, blend, store ----
    float pstp = cb[qg * 2368 + 2304 + lane];
#pragma unroll
    for (int r = 0; r < 16; ++r) {
        O[0][r] += cb[cbase + r];
        O[1][r] += cb[cbase + 16 + r];
    }
    float invv = 1.0f / (pst + pstp);

#pragma unroll
    for (int rg = 0; rg < 4; ++rg) {
#pragma unroll
        for (int rr = 0; rr < 4; ++rr) {
            const int reg = rg * 4 + rr;
            const int rl  = rr + 8 * rg + 4 * hi;       // local output row
            float inv = __shfl(invv, rl);               // broadcast from lane rl
            int row = row0 + qg * 32 + rl;
            size_t oo = (size_t)(b * Lv + row) * HE + h * Ev + l31;
            bool blend = w0blk && (rl == 0);
#pragma unroll
            for (int et = 0; et < 2; ++et) {
                float res = O[et][reg] * inv;
                if (blend) res = wgt * res + (1.f - wgt) * locv[et];
                if (ISBF) ((u16*)outv)[oo + et * 32] = f2bf(res);
                else      ((float*)outv)[oo + et * 32] = res;
            }
        }
    }
}

__global__ __launch_bounds__(512, 4) void attn_kernel_ws(
    const void* __restrict__ qv, const void* __restrict__ kv,
    const void* __restrict__ vv, const void* __restrict__ alphav,
    void* __restrict__ outv, const u16* __restrict__ ws)
{
    // 64 KB: 8 waves x (K tile 4 KB + V tile 4 KB), wave-private.
    // Reused as float scratch (9472 f32) for split-K combine at the end.
    __shared__ u16 SMEM[32768];
    const int isbf = detect_isbf16((const u32*)qv, threadIdx.x & 63);
    if (isbf) attn_impl<1, 1>(qv, kv, vv, alphav, outv, ws, SMEM);
    else      attn_impl<0, 1>(qv, kv, vv, alphav, outv, ws, SMEM);
}

__global__ __launch_bounds__(512, 4) void attn_kernel_nws(
    const void* __restrict__ qv, const void* __restrict__ kv,
    const void* __restrict__ vv, const void* __restrict__ alphav,
    void* __restrict__ outv)
{
    __shared__ u16 SMEM[32768];
    const int isbf = detect_isbf16((const u32*)qv, threadIdx.x & 63);
    if (isbf) attn_impl<1, 0>(qv, kv, vv, alphav, outv, nullptr, SMEM);
    else      attn_impl<0, 0>(qv, kv, vv, alphav, outv, nullptr, SMEM);
}

extern "C" void kernel_launch(void* const* d_in, const int* in_sizes, int n_in,
                              void* d_out, int out_size, void* d_ws, size_t ws_size,
                              hipStream_t stream) {
    if (d_ws != nullptr && ws_size >= WS_NEED) {
        hipLaunchKernelGGL(convert_kernel, dim3(2048), dim3(256), 0, stream,
                           d_in[0], d_in[1], d_in[2], (u16*)d_ws);
        hipLaunchKernelGGL(attn_kernel_ws, dim3(512), dim3(512), 0, stream,
                           d_in[0], d_in[1], d_in[2], d_in[3], d_out,
                           (const u16*)d_ws);
    } else {
        hipLaunchKernelGGL(attn_kernel_nws, dim3(512), dim3(512), 0, stream,
                           d_in[0], d_in[1], d_in[2], d_in[3], d_out);
    }
}

// Round 11
// 150.040 us; speedup vs baseline: 1.0358x; 1.0358x over previous
//
#include <hip/hip_runtime.h>

typedef unsigned short u16;
typedef unsigned int   u32;
typedef __attribute__((ext_vector_type(8))) short short8;   // 8 x bf16 (4 VGPRs)
typedef __attribute__((ext_vector_type(16))) float f32x16;

#define MFMA32(a, b, c) __builtin_amdgcn_mfma_f32_32x32x16_bf16(a, b, c, 0, 0, 0)

constexpr int Lv = 2048, Hv = 8, Ev = 64, HE = Hv * Ev; // HE=512
constexpr float QSCALE = 0.18033688011112042f;          // 0.125 * log2(e)
constexpr size_t WSV_OFF = 32u * 64u * 2048u;           // u16 offset of V images
#define WS_NEED ((size_t)16777216)

__device__ __forceinline__ float bf2f(u16 u) {
    u32 x = ((u32)u) << 16;
    return __builtin_bit_cast(float, x);
}
__device__ __forceinline__ u16 f2bf(float f) {   // RNE, finite inputs
    u32 x = __builtin_bit_cast(u32, f);
    u32 r = ((x >> 16) & 1u) + 0x7fffu;
    return (u16)((x + r) >> 16);
}
__device__ __forceinline__ u32 pkbf(float a, float b) {
#if __has_builtin(__builtin_amdgcn_cvt_pk_bf16_f32)
    typedef __attribute__((ext_vector_type(2))) __bf16 bf16x2;
    bf16x2 v = __builtin_amdgcn_cvt_pk_bf16_f32(a, b);
    return __builtin_bit_cast(u32, v);
#else
    return (u32)f2bf(a) | ((u32)f2bf(b) << 16);
#endif
}
__device__ __forceinline__ float fexp2(float x) {
#if __has_builtin(__builtin_amdgcn_exp2f)
    return __builtin_amdgcn_exp2f(x);
#else
    return exp2f(x);
#endif
}

// async global(16B/lane) -> LDS(base + lane*16). Guide §5 / m97 pattern.
__device__ __forceinline__ void gll16(const void* g, void* l) {
    __builtin_amdgcn_global_load_lds(
        (const __attribute__((address_space(1))) void*)g,
        (__attribute__((address_space(3))) void*)l, 16, 0, 0);
}

// Runtime dtype sniff (validated rounds 0-10: fp32 inputs detected correctly).
__device__ __forceinline__ int detect_isbf16(const u32* q32, int lane) {
    u32 w0 = q32[2 * lane];
    u32 w1 = q32[2 * lane + 1];
    u16 uu[4] = { (u16)(w0 & 0xffff), (u16)(w0 >> 16),
                  (u16)(w1 & 0xffff), (u16)(w1 >> 16) };
    int p = 0, z = 0;
#pragma unroll
    for (int j = 0; j < 4; ++j) {
        u16 mgn = (u16)(uu[j] & 0x7fff);
        int ex  = mgn >> 7;
        bool zero = (mgn == 0);
        bool pl   = zero || (ex >= 115 && ex <= 132);
        p += pl ? 1 : 0;
        if ((j & 1) == 0) z += zero ? 1 : 0;
    }
    int acc = p | (z << 16);
#pragma unroll
    for (int o = 1; o < 64; o <<= 1) acc += __shfl_xor(acc, o);
    int ps = acc & 0xffff, zs = acc >> 16;
    if (zs >= 100) return 0;
    return (ps >= 240) ? 1 : 0;
}

__device__ __forceinline__ short8 cvt8s(const float* p, float s) {
    float4 a = *(const float4*)p, b4 = *(const float4*)(p + 4);
    u32 r[4] = { pkbf(a.x * s, a.y * s), pkbf(a.z * s, a.w * s),
                 pkbf(b4.x * s, b4.y * s), pkbf(b4.z * s, b4.w * s) };
    return *(short8*)r;
}

__device__ __forceinline__ f32x16 zv16() {
    f32x16 z;
#pragma unroll
    for (int r = 0; r < 16; ++r) z[r] = 0.f;
    return z;
}

// Exchange a.hi-lanes <-> b.lo-lanes (v_permlane32_swap_b32 semantics).
__device__ __forceinline__ void plswap(u32& a, u32& b) {
#if __has_builtin(__builtin_amdgcn_permlane32_swap)
    auto r = __builtin_amdgcn_permlane32_swap(a, b, false, false);
    a = r[0]; b = r[1];
#else
    int lane = (int)(threadIdx.x & 63);
    u32 ax = (u32)__shfl_xor((int)a, 32);
    u32 bx = (u32)__shfl_xor((int)b, 32);
    bool hi = lane >= 32;
    u32 na = hi ? bx : a;
    u32 nb = hi ? b  : ax;
    a = na; b = nb;
#endif
}

// ---------------------------------------------------------------------------
// Convert kernel (round-11): same image layout as round 10, but the V
// transpose goes through a 4.25 KB LDS tile so GLOBAL reads are coalesced
// float4 row loads and GLOBAL writes are coalesced u32 image stores (the
// scatter happens in LDS, where it is cheap). K reads stay direct: each
// key's 64 e = 256 B contiguous region; swizzle only permutes within it.
// K image:  addr a: key=a>>6, sf=(a&63)>>3, j=a&7, e=((sf^(key&7))<<3)+j
// V image:  addr a: e=a>>5,  sf=(a&31)>>3, j=a&7, key=((sf^((e+(e>>3))&3))<<3)+j
//           u32 at even a packs keys {k0, k0+1} at same e.
// ---------------------------------------------------------------------------
template <int ISBF>
__device__ __forceinline__ void convert_impl(const void* kin, const void* vin,
                                             u16* __restrict__ ws, u16* VT) {
    const int blk = blockIdx.x;        // bh*64 + tg
    const int bh  = blk >> 6, tg = blk & 63;
    const int b   = bh >> 3,  h  = bh & 7;
    const size_t inb = (size_t)b * Lv * HE + h * Ev;
    u16* kimg = ws + (size_t)blk * 2048;
    u16* vimg = ws + WSV_OFF + (size_t)blk * 2048;
    const int t = threadIdx.x;         // 0..255

    // Phase 1: V rows -> VT[key*68 + e] (bf16), coalesced float4/uint2 reads.
#pragma unroll
    for (int r = 0; r < 2; ++r) {
        int f = t + 256 * r;           // 0..511
        int key = f >> 4, part = f & 15;
        size_t src = inb + (size_t)(tg * 32 + key) * HE + part * 4;
        if (ISBF) {
            uint2 vv_ = *(const uint2*)((const u16*)vin + src);
            *(uint2*)&VT[key * 68 + part * 4] = vv_;
        } else {
            float4 v = *(const float4*)((const float*)vin + src);
            *(u32*)&VT[key * 68 + part * 4]     = pkbf(v.x, v.y);
            *(u32*)&VT[key * 68 + part * 4 + 2] = pkbf(v.z, v.w);
        }
    }

    // K image: direct (no LDS dependency — overlaps V load latency).
#pragma unroll
    for (int r = 0; r < 4; ++r) {
        int i = t + 256 * r, a = 2 * i;
        int key = a >> 6, sf = (a & 63) >> 3, j0 = a & 7;
        int e0 = ((sf ^ (key & 7)) << 3) + j0;
        size_t s = inb + (size_t)(tg * 32 + key) * HE + e0;
        u32 val;
        if (ISBF) val = *(const u32*)((const u16*)kin + s);
        else { float2 kvv = *(const float2*)((const float*)kin + s);
               val = pkbf(kvv.x, kvv.y); }
        *(u32*)&kimg[a] = val;
    }

    __syncthreads();

    // Phase 2: V image, coalesced u32 writes; LDS handles the scatter.
#pragma unroll
    for (int r = 0; r < 4; ++r) {
        int i = t + 256 * r, a = 2 * i;
        int e = a >> 5, sf = (a & 31) >> 3, j0 = a & 7;
        int k0 = ((sf ^ ((e + (e >> 3)) & 3)) << 3) + j0;   // even; k0+1 <= 31
        u32 val = (u32)VT[k0 * 68 + e] | ((u32)VT[(k0 + 1) * 68 + e] << 16);
        *(u32*)&vimg[a] = val;
    }
}

__global__ __launch_bounds__(256) void convert_kernel(
    const void* __restrict__ qv, const void* __restrict__ kv,
    const void* __restrict__ vv, u16* __restrict__ ws)
{
    __shared__ u16 VT[32 * 68];        // 4.25 KB transpose tile
    const int isbf = detect_isbf16((const u32*)qv, threadIdx.x & 63);
    if (isbf) convert_impl<1>(kv, vv, ws, VT);
    else      convert_impl<0>(kv, vv, ws, VT);
}

// ---------------------------------------------------------------------------
// Fused full attention + l=0 local blend.  Round-11 = round-10 barrier-free
// structure with staging moved to global_load_lds (T-catalog):
//   * 8 x gll(16B) per tile replaces 8 loads + 8 ds_writes + 16 prefetch
//     VGPRs — the SIMD issue port is the measured limiter (320 issue-cy per
//     wave-kt; staging is the largest removable slice).
//   * Wave-private counted-vmcnt sync, never 0 in the loop:
//       top of iter:  vmcnt(4)  -> K(kt) landed (FIFO oldest 4)
//       after QK:     lgkmcnt(0) -> K reads retired; issue gll K(kt+1)
//       mid iter:     vmcnt(4)  -> V(kt) landed
//       after PV:     lgkmcnt(0) -> V reads retired; issue gll V(kt+1)
//     Every asm wait is followed by sched_barrier(0) (rule #18).
// Geometry unchanged: 512 blocks x 512 thr, wave = (qg: 32 q) x (g: 1024
// keys), wave-private 8 KB LDS slice, NO s_barrier in the K-loop.
// WS=0 fallback: round-10 direct-staging path, unchanged.
// ---------------------------------------------------------------------------
template <int ISBF, int WS>
__device__ __forceinline__ void attn_impl(
    const void* __restrict__ qv, const void* __restrict__ kv,
    const void* __restrict__ vv, const void* __restrict__ alphav,
    void* __restrict__ outv, const u16* __restrict__ ws, u16* SMEM)
{
    const int tid  = threadIdx.x;       // 0..511
    const int w    = tid >> 6;          // wave 0..7
    const int lane = tid & 63;
    const int l31  = lane & 31;
    const int hi   = lane >> 5;
    const int qg   = w & 3;             // query sub-block (32 rows)
    const int g    = w >> 2;            // key-half group (1024 keys)

    // XCD-aware mapping: xcd = fid&7 handles bh in {4*xcd .. 4*xcd+3}.
    const int fid = blockIdx.x;         // 0..511
    const int bh  = (fid & 7) * 4 + ((fid >> 3) & 3);
    const int rb  = fid >> 5;           // 0..15
    const int b   = bh >> 3, h = bh & 7;
    const int row0 = rb * 128;

    const size_t bhoff = (size_t)b * Lv * HE + h * Ev;
    const u16*   q16 = (const u16*)qv + bhoff;
    const u16*   k16 = (const u16*)kv + bhoff;
    const u16*   v16 = (const u16*)vv + bhoff;
    const float* q32 = (const float*)qv + bhoff;
    const float* k32 = (const float*)kv + bhoff;
    const float* v32 = (const float*)vv + bhoff;

    // wave-private LDS slice: K tile [32 key][64 e] + V tile [64 e][32 key]
    u16* ldsK = SMEM + w * 4096;
    u16* ldsV = ldsK + 2048;

    // Q fragments (pre-scaled). qf[c][j] = Qs[row0+qg*32+l31][16c+8hi+j].
    short8 qf[4];
    {
        size_t ro = (size_t)(row0 + qg * 32 + l31) * HE + hi * 8;
        if (ISBF) {
#pragma unroll
            for (int c = 0; c < 4; ++c) {
                short8 t = *(const short8*)(q16 + ro + 16 * c);
#pragma unroll
                for (int j = 0; j < 8; ++j)
                    qf[c][j] = (short)f2bf(bf2f((u16)t[j]) * QSCALE);
            }
        } else {
#pragma unroll
            for (int c = 0; c < 4; ++c) qf[c] = cvt8s(q32 + ro + 16 * c, QSCALE);
        }
    }

    f32x16 O[2];
    O[0] = zv16(); O[1] = zv16();
    float psum = 0.f;

    // image bases (WS=1): tile tg = g*32 + kt
    const u16* kimg0 = ws + ((size_t)bh * 64 + g * 32) * 2048;
    const u16* vimg0 = ws + WSV_OFF + ((size_t)bh * 64 + g * 32) * 2048;
    const size_t keybase = (size_t)g * 1024;     // WS=0 global key offset

    // WS=0 staging lane mapping
    const int k0l = lane >> 3;
    const int kj  = lane & 7;
    const int e0K = ((kj ^ k0l) << 3);
    const int eoV = kj * 8;

    // WS=0 prefetch registers
    float4 fpa, fpb, fpc, fpd;
    uint4  upa, upb;

    // ---------------- WS=1 gll staging ----------------
#define GLLK(KT) do {                                                          \
        const u16* ib_ = kimg0 + (size_t)(KT) * 2048 + lane * 8;               \
        _Pragma("unroll")                                                      \
        for (int s_ = 0; s_ < 4; ++s_)                                         \
            gll16(ib_ + s_ * 512, ldsK + s_ * 512);                            \
    } while (0)
#define GLLV(KT) do {                                                          \
        const u16* ib_ = vimg0 + (size_t)(KT) * 2048 + lane * 8;               \
        _Pragma("unroll")                                                      \
        for (int s_ = 0; s_ < 4; ++s_)                                         \
            gll16(ib_ + s_ * 512, ldsV + s_ * 512);                            \
    } while (0)
#define WAITV4() do { asm volatile("s_waitcnt vmcnt(4)" ::: "memory");         \
        __builtin_amdgcn_sched_barrier(0); } while (0)
#define WAITV0() do { asm volatile("s_waitcnt vmcnt(0)" ::: "memory");         \
        __builtin_amdgcn_sched_barrier(0); } while (0)
#define WAITL0() do { asm volatile("s_waitcnt lgkmcnt(0)" ::: "memory");       \
        __builtin_amdgcn_sched_barrier(0); } while (0)

    // ---------------- WS=0 staging (round-10, unchanged) ----------------
#define LK0(KT, CH) do {                                                       \
        size_t tb_ = (keybase + (size_t)(KT) * 32) * HE;                       \
        int key_ = (CH) * 16 + k0l;                                            \
        if (ISBF) {                                                            \
            const u16* p_ = k16 + tb_ + (size_t)key_ * HE + e0K;               \
            upa = *(const uint4*)p_;                                           \
            upb = *(const uint4*)(p_ + 8 * HE);                                \
        } else {                                                               \
            const float* p_ = k32 + tb_ + (size_t)key_ * HE + e0K;             \
            fpa = *(const float4*)p_;            fpb = *(const float4*)(p_ + 4);\
            fpc = *(const float4*)(p_ + 8 * HE); fpd = *(const float4*)(p_ + 8 * HE + 4);\
        }                                                                      \
    } while (0)
#define SK0(CH) do {                                                           \
        if (ISBF) {                                                            \
            *(uint4*)&ldsK[((CH)*2    ) * 512 + lane * 8] = upa;               \
            *(uint4*)&ldsK[((CH)*2 + 1) * 512 + lane * 8] = upb;               \
        } else {                                                               \
            u32 t0_[4] = { pkbf(fpa.x, fpa.y), pkbf(fpa.z, fpa.w),             \
                           pkbf(fpb.x, fpb.y), pkbf(fpb.z, fpb.w) };           \
            u32 t1_[4] = { pkbf(fpc.x, fpc.y), pkbf(fpc.z, fpc.w),             \
                           pkbf(fpd.x, fpd.y), pkbf(fpd.z, fpd.w) };           \
            *(uint4*)&ldsK[((CH)*2    ) * 512 + lane * 8] = *(uint4*)t0_;      \
            *(uint4*)&ldsK[((CH)*2 + 1) * 512 + lane * 8] = *(uint4*)t1_;      \
        }                                                                      \
    } while (0)
#define LV0(KT, VH) do {                                                       \
        size_t tb_ = (keybase + (size_t)(KT) * 32 + (VH) * 16 + 2 * k0l) * HE; \
        if (ISBF) {                                                            \
            const u16* p_ = v16 + tb_ + eoV;                                   \
            upa = *(const uint4*)p_;                                           \
            upb = *(const uint4*)(p_ + HE);                                    \
        } else {                                                               \
            const float* p_ = v32 + tb_ + eoV;                                 \
            fpa = *(const float4*)p_;       fpb = *(const float4*)(p_ + 4);    \
            fpc = *(const float4*)(p_ + HE); fpd = *(const float4*)(p_ + HE + 4);\
        }                                                                      \
    } while (0)
#define SV0(VH) do {                                                           \
        int s_ = (k0l >> 2) + (VH) * 2;                                        \
        if (ISBF) {                                                            \
            const u16* a0_ = (const u16*)&upa;                                 \
            const u16* a1_ = (const u16*)&upb;                                 \
            _Pragma("unroll")                                                  \
            for (int j = 0; j < 8; ++j) {                                      \
                int e_ = eoV + j;                                              \
                int sl_ = s_ ^ ((e_ + (e_ >> 3)) & 3);                         \
                *(u32*)&ldsV[e_ * 32 + sl_ * 8 + ((2 * k0l) & 7)] =            \
                    (u32)a0_[j] | ((u32)a1_[j] << 16);                         \
            }                                                                  \
        } else {                                                               \
            float t0_[8] = {fpa.x, fpa.y, fpa.z, fpa.w, fpb.x, fpb.y, fpb.z, fpb.w};\
            float t1_[8] = {fpc.x, fpc.y, fpc.z, fpc.w, fpd.x, fpd.y, fpd.z, fpd.w};\
            _Pragma("unroll")                                                  \
            for (int j = 0; j < 8; ++j) {                                      \
                int e_ = eoV + j;                                              \
                int sl_ = s_ ^ ((e_ + (e_ >> 3)) & 3);                         \
                *(u32*)&ldsV[e_ * 32 + sl_ * 8 + ((2 * k0l) & 7)] =            \
                    pkbf(t0_[j], t1_[j]);                                      \
            }                                                                  \
        }                                                                      \
    } while (0)

    // ---------------- compute macros ----------------
    f32x16 St;
#define QK_() do {                                                             \
        St = zv16();                                                           \
        __builtin_amdgcn_s_setprio(1);                                         \
        _Pragma("unroll")                                                      \
        for (int c = 0; c < 4; ++c) {                                          \
            int sl = (2 * c + hi) ^ (l31 & 7);                                 \
            short8 kf = *(const short8*)&ldsK[l31 * 64 + sl * 8];              \
            St = MFMA32(kf, qf[c], St);                                        \
        }                                                                      \
        __builtin_amdgcn_s_setprio(0);                                         \
    } while (0)

    u32 c8[8];
#define SM_() do {                                                             \
        _Pragma("unroll")                                                      \
        for (int r = 0; r < 16; ++r) St[r] = fexp2(St[r]);                     \
        _Pragma("unroll")                                                      \
        for (int r = 0; r < 16; ++r) psum += St[r];                            \
        _Pragma("unroll")                                                      \
        for (int q = 0; q < 8; ++q) c8[q] = pkbf(St[2 * q], St[2 * q + 1]);    \
    } while (0)

#define PV_(T) do {                                                            \
        u32 a0 = c8[4 * (T) + 0], a1 = c8[4 * (T) + 1];                        \
        u32 a2 = c8[4 * (T) + 2], a3 = c8[4 * (T) + 3];                        \
        plswap(a0, a2);                                                        \
        plswap(a1, a3);                                                        \
        u32 pw_[4] = { a0, a1, a2, a3 };                                       \
        short8 pa = *(short8*)pw_;                                             \
        __builtin_amdgcn_s_setprio(1);                                         \
        _Pragma("unroll")                                                      \
        for (int et = 0; et < 2; ++et) {                                       \
            int e  = et * 32 + l31;                                            \
            int sl = (2 * (T) + hi) ^ ((e + (e >> 3)) & 3);                    \
            short8 vf = *(const short8*)&ldsV[e * 32 + sl * 8];                \
            O[et] = MFMA32(pa, vf, O[et]);                                     \
        }                                                                      \
        __builtin_amdgcn_s_setprio(0);                                         \
    } while (0)

    // ---------------- barrier-free K-loop ----------------
    if (WS) {
        GLLK(0); GLLV(0);                       // outstanding: K0(4) V0(4)
        for (int kt = 0; kt < 31; ++kt) {
            WAITV4();                           // K(kt) landed
            QK_();
            WAITL0();                           // K reads retired
            GLLK(kt + 1);                       // outstanding V(kt)4 + K4
            SM_();
            WAITV4();                           // V(kt) landed
            PV_(0);
            PV_(1);
            WAITL0();                           // V reads retired
            GLLV(kt + 1);                       // outstanding K4 + V4
        }
        WAITV0();                               // K31, V31 landed
        QK_();
        SM_();
        PV_(0);
        PV_(1);
    } else {
        LK0(0, 0); SK0(0); LK0(0, 1); SK0(1);
        LV0(0, 0); SV0(0); LV0(0, 1); SV0(1);
        for (int kt = 0; kt < 32; ++kt) {
            if (kt < 31) LK0(kt + 1, 0);
            QK_();
            if (kt < 31) { SK0(0); LK0(kt + 1, 1); }
            SM_();
            if (kt < 31) { SK0(1); LV0(kt + 1, 0); }
            PV_(0);
            if (kt < 31) { SV0(0); LV0(kt + 1, 1); }
            PV_(1);
            if (kt < 31) SV0(1);
        }
    }
#undef GLLK
#undef GLLV
#undef WAITV4
#undef WAITV0
#undef WAITL0
#undef LK0
#undef SK0
#undef LV0
#undef SV0
#undef QK_
#undef SM_
#undef PV_

    // ---- combine the two key-halves through LDS (exact, unnormalized) ----
    __syncthreads();                              // all waves done with tiles
    float pst = psum + __shfl_xor(psum, 32);      // row sum over this half
    float* cb = (float*)SMEM;                     // tiles dead; reuse as f32
    const int cbase = qg * 2368 + lane * 36;      // 36 f32 stride: 16B-aligned

    if (g == 1) {
        union { f32x16 v; float4 q4[4]; } u;
        u.v = O[0];
#pragma unroll
        for (int i = 0; i < 4; ++i) *(float4*)&cb[cbase + 4 * i] = u.q4[i];
        u.v = O[1];
#pragma unroll
        for (int i = 0; i < 4; ++i) *(float4*)&cb[cbase + 16 + 4 * i] = u.q4[i];
        cb[qg * 2368 + 2304 + lane] = pst;
    }

    // ---- l=0 local attention (wave 0 = qg0/g0 of rb==0 blocks) ----
    float locv[2] = {0.f, 0.f};
    float wgt = 0.f;
    const bool w0blk = (rb == 0) && (w == 0);
    if (w0blk) {
        const int e = lane;
        const size_t base = bhoff + e;
#define LDIN(p, i) (ISBF ? bf2f(((const u16*)(p))[i]) : ((const float*)(p))[i])
        float qe = LDIN(qv, base);
        float s[9];
#pragma unroll
        for (int j = 0; j < 9; ++j) {
            float prod = qe * LDIN(kv, base + (size_t)j * HE);
#pragma unroll
            for (int o = 1; o < 64; o <<= 1) prod += __shfl_xor(prod, o);
            s[j] = prod * 0.125f;
        }
        float mx = s[0];
#pragma unroll
        for (int j = 1; j < 9; ++j) mx = fmaxf(mx, s[j]);
        float we[9];
#pragma unroll
        for (int j = 0; j < 9; ++j) we[j] = expf(s[j] - mx);
        float denom = 9.f * we[0];
        float acc   = 9.f * we[0] * LDIN(vv, base);
#pragma unroll
        for (int j = 1; j < 9; ++j) {
            denom += we[j];
            acc   += we[j] * LDIN(vv, base + (size_t)j * HE);
        }
        float loc = acc / denom;

        float a;
        if (ISBF) {
            a = bf2f(((const u16*)alphav)[0]);
            if (!(a >= 0.0f && a <= 1.0f)) {
                float af = ((const float*)alphav)[0];
                if (af >= 0.0f && af <= 1.0f) a = af;
            }
        } else {
            a = ((const float*)alphav)[0];
            if (!(a >= 0.0f && a <= 1.0f)) {
                float ab = bf2f(((const u16*)alphav)[0]);
                if (ab >= 0.0f && ab <= 1.0f) a = ab;
            }
        }
        wgt = 1.f / (1.f + expf(-a));
#pragma unroll
        for (int et = 0; et < 2; ++et) locv[et] = __shfl(loc, et * 32 + l31);
#undef LDIN
    }

    __syncthreads();                              // partials visible
    if (g != 0) return;

    // ---- g==0 waves: add partner partials, normalize, blend, store ----
    float pstp = cb[qg * 2368 + 2304 + lane];
#pragma unroll
    for (int r = 0; r < 16; ++r) {
        O[0][r] += cb[cbase + r];
        O[1][r] += cb[cbase + 16 + r];
    }
    float invv = 1.0f / (pst + pstp);

#pragma unroll
    for (int rg = 0; rg < 4; ++rg) {
#pragma unroll
        for (int rr = 0; rr < 4; ++rr) {
            const int reg = rg * 4 + rr;
            const int rl  = rr + 8 * rg + 4 * hi;       // local output row
            float inv = __shfl(invv, rl);               // broadcast from lane rl
            int row = row0 + qg * 32 + rl;
            size_t oo = (size_t)(b * Lv + row) * HE + h * Ev + l31;
            bool blend = w0blk && (rl == 0);
#pragma unroll
            for (int et = 0; et < 2; ++et) {
                float res = O[et][reg] * inv;
                if (blend) res = wgt * res + (1.f - wgt) * locv[et];
                if (ISBF) ((u16*)outv)[oo + et * 32] = f2bf(res);
                else      ((float*)outv)[oo + et * 32] = res;
            }
        }
    }
}

__global__ __launch_bounds__(512, 4) void attn_kernel_ws(
    const void* __restrict__ qv, const void* __restrict__ kv,
    const void* __restrict__ vv, const void* __restrict__ alphav,
    void* __restrict__ outv, const u16* __restrict__ ws)
{
    // 64 KB: 8 waves x (K tile 4 KB + V tile 4 KB), wave-private.
    // Reused as float scratch (9472 f32) for split-K combine at the end.
    __shared__ u16 SMEM[32768];
    const int isbf = detect_isbf16((const u32*)qv, threadIdx.x & 63);
    if (isbf) attn_impl<1, 1>(qv, kv, vv, alphav, outv, ws, SMEM);
    else      attn_impl<0, 1>(qv, kv, vv, alphav, outv, ws, SMEM);
}

__global__ __launch_bounds__(512, 4) void attn_kernel_nws(
    const void* __restrict__ qv, const void* __restrict__ kv,
    const void* __restrict__ vv, const void* __restrict__ alphav,
    void* __restrict__ outv)
{
    __shared__ u16 SMEM[32768];
    const int isbf = detect_isbf16((const u32*)qv, threadIdx.x & 63);
    if (isbf) attn_impl<1, 0>(qv, kv, vv, alphav, outv, nullptr, SMEM);
    else      attn_impl<0, 0>(qv, kv, vv, alphav, outv, nullptr, SMEM);
}

extern "C" void kernel_launch(void* const* d_in, const int* in_sizes, int n_in,
                              void* d_out, int out_size, void* d_ws, size_t ws_size,
                              hipStream_t stream) {
    if (d_ws != nullptr && ws_size >= WS_NEED) {
        hipLaunchKernelGGL(convert_kernel, dim3(2048), dim3(256), 0, stream,
                           d_in[0], d_in[1], d_in[2], (u16*)d_ws);
        hipLaunchKernelGGL(attn_kernel_ws, dim3(512), dim3(512), 0, stream,
                           d_in[0], d_in[1], d_in[2], d_in[3], d_out,
                           (const u16*)d_ws);
    } else {
        hipLaunchKernelGGL(attn_kernel_nws, dim3(512), dim3(512), 0, stream,
                           d_in[0], d_in[1], d_in[2], d_in[3], d_out);
    }
}

// Round 12
// 146.967 us; speedup vs baseline: 1.0574x; 1.0209x over previous
//
#include <hip/hip_runtime.h>

typedef unsigned short u16;
typedef unsigned int   u32;
typedef __attribute__((ext_vector_type(8))) short short8;   // 8 x bf16 (4 VGPRs)
typedef __attribute__((ext_vector_type(16))) float f32x16;

#define MFMA32(a, b, c) __builtin_amdgcn_mfma_f32_32x32x16_bf16(a, b, c, 0, 0, 0)

constexpr int Lv = 2048, Hv = 8, Ev = 64, HE = Hv * Ev; // HE=512
constexpr float QSCALE = 0.18033688011112042f;          // 0.125 * log2(e)
constexpr size_t WSV_OFF = 32u * 64u * 2048u;           // u16 offset of V images
#define WS_NEED ((size_t)16777216)

__device__ __forceinline__ float bf2f(u16 u) {
    u32 x = ((u32)u) << 16;
    return __builtin_bit_cast(float, x);
}
__device__ __forceinline__ u16 f2bf(float f) {   // RNE, finite inputs
    u32 x = __builtin_bit_cast(u32, f);
    u32 r = ((x >> 16) & 1u) + 0x7fffu;
    return (u16)((x + r) >> 16);
}
__device__ __forceinline__ u32 pkbf(float a, float b) {
#if __has_builtin(__builtin_amdgcn_cvt_pk_bf16_f32)
    typedef __attribute__((ext_vector_type(2))) __bf16 bf16x2;
    bf16x2 v = __builtin_amdgcn_cvt_pk_bf16_f32(a, b);
    return __builtin_bit_cast(u32, v);
#else
    return (u32)f2bf(a) | ((u32)f2bf(b) << 16);
#endif
}
__device__ __forceinline__ float fexp2(float x) {
#if __has_builtin(__builtin_amdgcn_exp2f)
    return __builtin_amdgcn_exp2f(x);
#else
    return exp2f(x);
#endif
}

// async global(16B/lane) -> LDS(base + lane*16). Guide §5 / m97 pattern.
__device__ __forceinline__ void gll16(const void* g, void* l) {
    __builtin_amdgcn_global_load_lds(
        (const __attribute__((address_space(1))) void*)g,
        (__attribute__((address_space(3))) void*)l, 16, 0, 0);
}

// Runtime dtype sniff (validated rounds 0-11: fp32 inputs detected correctly).
__device__ __forceinline__ int detect_isbf16(const u32* q32, int lane) {
    u32 w0 = q32[2 * lane];
    u32 w1 = q32[2 * lane + 1];
    u16 uu[4] = { (u16)(w0 & 0xffff), (u16)(w0 >> 16),
                  (u16)(w1 & 0xffff), (u16)(w1 >> 16) };
    int p = 0, z = 0;
#pragma unroll
    for (int j = 0; j < 4; ++j) {
        u16 mgn = (u16)(uu[j] & 0x7fff);
        int ex  = mgn >> 7;
        bool zero = (mgn == 0);
        bool pl   = zero || (ex >= 115 && ex <= 132);
        p += pl ? 1 : 0;
        if ((j & 1) == 0) z += zero ? 1 : 0;
    }
    int acc = p | (z << 16);
#pragma unroll
    for (int o = 1; o < 64; o <<= 1) acc += __shfl_xor(acc, o);
    int ps = acc & 0xffff, zs = acc >> 16;
    if (zs >= 100) return 0;
    return (ps >= 240) ? 1 : 0;
}

__device__ __forceinline__ short8 cvt8s(const float* p, float s) {
    float4 a = *(const float4*)p, b4 = *(const float4*)(p + 4);
    u32 r[4] = { pkbf(a.x * s, a.y * s), pkbf(a.z * s, a.w * s),
                 pkbf(b4.x * s, b4.y * s), pkbf(b4.z * s, b4.w * s) };
    return *(short8*)r;
}

__device__ __forceinline__ f32x16 zv16() {
    f32x16 z;
#pragma unroll
    for (int r = 0; r < 16; ++r) z[r] = 0.f;
    return z;
}

// Exchange a.hi-lanes <-> b.lo-lanes (v_permlane32_swap_b32 semantics).
__device__ __forceinline__ void plswap(u32& a, u32& b) {
#if __has_builtin(__builtin_amdgcn_permlane32_swap)
    auto r = __builtin_amdgcn_permlane32_swap(a, b, false, false);
    a = r[0]; b = r[1];
#else
    int lane = (int)(threadIdx.x & 63);
    u32 ax = (u32)__shfl_xor((int)a, 32);
    u32 bx = (u32)__shfl_xor((int)b, 32);
    bool hi = lane >= 32;
    u32 na = hi ? bx : a;
    u32 nb = hi ? b  : ax;
    a = na; b = nb;
#endif
}

// ---------------------------------------------------------------------------
// Convert kernel (round-11 version, unchanged): K/V -> pre-swizzled bf16
// images in ws; V transpose through a 4.25 KB LDS tile for coalescing.
// K image:  addr a: key=a>>6, sf=(a&63)>>3, j=a&7, e=((sf^(key&7))<<3)+j
// V image:  addr a: e=a>>5,  sf=(a&31)>>3, j=a&7, key=((sf^((e+(e>>3))&3))<<3)+j
// ---------------------------------------------------------------------------
template <int ISBF>
__device__ __forceinline__ void convert_impl(const void* kin, const void* vin,
                                             u16* __restrict__ ws, u16* VT) {
    const int blk = blockIdx.x;        // bh*64 + tg
    const int bh  = blk >> 6, tg = blk & 63;
    const int b   = bh >> 3,  h  = bh & 7;
    const size_t inb = (size_t)b * Lv * HE + h * Ev;
    u16* kimg = ws + (size_t)blk * 2048;
    u16* vimg = ws + WSV_OFF + (size_t)blk * 2048;
    const int t = threadIdx.x;         // 0..255

#pragma unroll
    for (int r = 0; r < 2; ++r) {
        int f = t + 256 * r;           // 0..511
        int key = f >> 4, part = f & 15;
        size_t src = inb + (size_t)(tg * 32 + key) * HE + part * 4;
        if (ISBF) {
            uint2 vv_ = *(const uint2*)((const u16*)vin + src);
            *(uint2*)&VT[key * 68 + part * 4] = vv_;
        } else {
            float4 v = *(const float4*)((const float*)vin + src);
            *(u32*)&VT[key * 68 + part * 4]     = pkbf(v.x, v.y);
            *(u32*)&VT[key * 68 + part * 4 + 2] = pkbf(v.z, v.w);
        }
    }

#pragma unroll
    for (int r = 0; r < 4; ++r) {
        int i = t + 256 * r, a = 2 * i;
        int key = a >> 6, sf = (a & 63) >> 3, j0 = a & 7;
        int e0 = ((sf ^ (key & 7)) << 3) + j0;
        size_t s = inb + (size_t)(tg * 32 + key) * HE + e0;
        u32 val;
        if (ISBF) val = *(const u32*)((const u16*)kin + s);
        else { float2 kvv = *(const float2*)((const float*)kin + s);
               val = pkbf(kvv.x, kvv.y); }
        *(u32*)&kimg[a] = val;
    }

    __syncthreads();

#pragma unroll
    for (int r = 0; r < 4; ++r) {
        int i = t + 256 * r, a = 2 * i;
        int e = a >> 5, sf = (a & 31) >> 3, j0 = a & 7;
        int k0 = ((sf ^ ((e + (e >> 3)) & 3)) << 3) + j0;   // even; k0+1 <= 31
        u32 val = (u32)VT[k0 * 68 + e] | ((u32)VT[(k0 + 1) * 68 + e] << 16);
        *(u32*)&vimg[a] = val;
    }
}

__global__ __launch_bounds__(256) void convert_kernel(
    const void* __restrict__ qv, const void* __restrict__ kv,
    const void* __restrict__ vv, u16* __restrict__ ws)
{
    __shared__ u16 VT[32 * 68];        // 4.25 KB transpose tile
    const int isbf = detect_isbf16((const u32*)qv, threadIdx.x & 63);
    if (isbf) convert_impl<1>(kv, vv, ws, VT);
    else      convert_impl<0>(kv, vv, ws, VT);
}

// ---------------------------------------------------------------------------
// Fused full attention + l=0 local blend.  Round-12 = round-11 barrier-free
// gll structure + att[2] (T15) double-pipeline:
//   * Region A of iter kt: QK(kt)->St_cur (ds_read+MFMA stream) runs in the
//     SAME scheduling region as SM(St_prev) (exp2/pack VALU stream on tile
//     kt-1's scores) — data-independent, so the compiler interleaves MFMA
//     and VALU, removing the ~150cy SM link from the serial chain that
//     R11 measured as the wall (issue-count cut was flat; chain is the wall).
//   * Region B: PV(kt-1).  gll issue points keep R11's latency windows:
//     GLLK(kt+1) after region A (lands under PV + next region A),
//     GLLV(kt) at iter end (lands under next region A).
//   * St ping-pong StA/StB: static names, loop unrolled x2 (rule #20).
//   * Registers: gll staging freed the prefetch regs (R11 VGPR=56), so the
//     second St (+16) fits ~105 live < 128. Spill check = WRITE_SIZE.
//   * Counted vmcnt(4) at waits; never a mid-loop drain; every asm wait is
//     followed by sched_barrier(0) (rule #18).
// Geometry unchanged: 512 blocks x 512 thr, wave = (qg: 32 q) x (g: 1024
// keys), wave-private 8 KB LDS slice, NO s_barrier in the K-loop.
// WS=0 fallback: round-10 direct-staging path, unchanged.
// ---------------------------------------------------------------------------
template <int ISBF, int WS>
__device__ __forceinline__ void attn_impl(
    const void* __restrict__ qv, const void* __restrict__ kv,
    const void* __restrict__ vv, const void* __restrict__ alphav,
    void* __restrict__ outv, const u16* __restrict__ ws, u16* SMEM)
{
    const int tid  = threadIdx.x;       // 0..511
    const int w    = tid >> 6;          // wave 0..7
    const int lane = tid & 63;
    const int l31  = lane & 31;
    const int hi   = lane >> 5;
    const int qg   = w & 3;             // query sub-block (32 rows)
    const int g    = w >> 2;            // key-half group (1024 keys)

    // XCD-aware mapping: xcd = fid&7 handles bh in {4*xcd .. 4*xcd+3}.
    const int fid = blockIdx.x;         // 0..511
    const int bh  = (fid & 7) * 4 + ((fid >> 3) & 3);
    const int rb  = fid >> 5;           // 0..15
    const int b   = bh >> 3, h = bh & 7;
    const int row0 = rb * 128;

    const size_t bhoff = (size_t)b * Lv * HE + h * Ev;
    const u16*   q16 = (const u16*)qv + bhoff;
    const u16*   k16 = (const u16*)kv + bhoff;
    const u16*   v16 = (const u16*)vv + bhoff;
    const float* q32 = (const float*)qv + bhoff;
    const float* k32 = (const float*)kv + bhoff;
    const float* v32 = (const float*)vv + bhoff;

    // wave-private LDS slice: K tile [32 key][64 e] + V tile [64 e][32 key]
    u16* ldsK = SMEM + w * 4096;
    u16* ldsV = ldsK + 2048;

    // Q fragments (pre-scaled). qf[c][j] = Qs[row0+qg*32+l31][16c+8hi+j].
    short8 qf[4];
    {
        size_t ro = (size_t)(row0 + qg * 32 + l31) * HE + hi * 8;
        if (ISBF) {
#pragma unroll
            for (int c = 0; c < 4; ++c) {
                short8 t = *(const short8*)(q16 + ro + 16 * c);
#pragma unroll
                for (int j = 0; j < 8; ++j)
                    qf[c][j] = (short)f2bf(bf2f((u16)t[j]) * QSCALE);
            }
        } else {
#pragma unroll
            for (int c = 0; c < 4; ++c) qf[c] = cvt8s(q32 + ro + 16 * c, QSCALE);
        }
    }

    f32x16 O[2];
    O[0] = zv16(); O[1] = zv16();
    f32x16 StA = zv16(), StB = zv16();   // att[2] ping-pong score states
    float psum = 0.f;

    // image bases (WS=1): tile tg = g*32 + kt
    const u16* kimg0 = ws + ((size_t)bh * 64 + g * 32) * 2048;
    const u16* vimg0 = ws + WSV_OFF + ((size_t)bh * 64 + g * 32) * 2048;
    const size_t keybase = (size_t)g * 1024;     // WS=0 global key offset

    // WS=0 staging lane mapping
    const int k0l = lane >> 3;
    const int kj  = lane & 7;
    const int e0K = ((kj ^ k0l) << 3);
    const int eoV = kj * 8;

    // WS=0 prefetch registers
    float4 fpa, fpb, fpc, fpd;
    uint4  upa, upb;

    // ---------------- WS=1 gll staging ----------------
#define GLLK(KT) do {                                                          \
        const u16* ib_ = kimg0 + (size_t)(KT) * 2048 + lane * 8;               \
        _Pragma("unroll")                                                      \
        for (int s_ = 0; s_ < 4; ++s_)                                         \
            gll16(ib_ + s_ * 512, ldsK + s_ * 512);                            \
    } while (0)
#define GLLV(KT) do {                                                          \
        const u16* ib_ = vimg0 + (size_t)(KT) * 2048 + lane * 8;               \
        _Pragma("unroll")                                                      \
        for (int s_ = 0; s_ < 4; ++s_)                                         \
            gll16(ib_ + s_ * 512, ldsV + s_ * 512);                            \
    } while (0)
#define WAITV4() do { asm volatile("s_waitcnt vmcnt(4)" ::: "memory");         \
        __builtin_amdgcn_sched_barrier(0); } while (0)
#define WAITV0() do { asm volatile("s_waitcnt vmcnt(0)" ::: "memory");         \
        __builtin_amdgcn_sched_barrier(0); } while (0)
#define WAITL0() do { asm volatile("s_waitcnt lgkmcnt(0)" ::: "memory");       \
        __builtin_amdgcn_sched_barrier(0); } while (0)

    // ---------------- WS=0 staging (round-10, unchanged) ----------------
#define LK0(KT, CH) do {                                                       \
        size_t tb_ = (keybase + (size_t)(KT) * 32) * HE;                       \
        int key_ = (CH) * 16 + k0l;                                            \
        if (ISBF) {                                                            \
            const u16* p_ = k16 + tb_ + (size_t)key_ * HE + e0K;               \
            upa = *(const uint4*)p_;                                           \
            upb = *(const uint4*)(p_ + 8 * HE);                                \
        } else {                                                               \
            const float* p_ = k32 + tb_ + (size_t)key_ * HE + e0K;             \
            fpa = *(const float4*)p_;            fpb = *(const float4*)(p_ + 4);\
            fpc = *(const float4*)(p_ + 8 * HE); fpd = *(const float4*)(p_ + 8 * HE + 4);\
        }                                                                      \
    } while (0)
#define SK0(CH) do {                                                           \
        if (ISBF) {                                                            \
            *(uint4*)&ldsK[((CH)*2    ) * 512 + lane * 8] = upa;               \
            *(uint4*)&ldsK[((CH)*2 + 1) * 512 + lane * 8] = upb;               \
        } else {                                                               \
            u32 t0_[4] = { pkbf(fpa.x, fpa.y), pkbf(fpa.z, fpa.w),             \
                           pkbf(fpb.x, fpb.y), pkbf(fpb.z, fpb.w) };           \
            u32 t1_[4] = { pkbf(fpc.x, fpc.y), pkbf(fpc.z, fpc.w),             \
                           pkbf(fpd.x, fpd.y), pkbf(fpd.z, fpd.w) };           \
            *(uint4*)&ldsK[((CH)*2    ) * 512 + lane * 8] = *(uint4*)t0_;      \
            *(uint4*)&ldsK[((CH)*2 + 1) * 512 + lane * 8] = *(uint4*)t1_;      \
        }                                                                      \
    } while (0)
#define LV0(KT, VH) do {                                                       \
        size_t tb_ = (keybase + (size_t)(KT) * 32 + (VH) * 16 + 2 * k0l) * HE; \
        if (ISBF) {                                                            \
            const u16* p_ = v16 + tb_ + eoV;                                   \
            upa = *(const uint4*)p_;                                           \
            upb = *(const uint4*)(p_ + HE);                                    \
        } else {                                                               \
            const float* p_ = v32 + tb_ + eoV;                                 \
            fpa = *(const float4*)p_;       fpb = *(const float4*)(p_ + 4);    \
            fpc = *(const float4*)(p_ + HE); fpd = *(const float4*)(p_ + HE + 4);\
        }                                                                      \
    } while (0)
#define SV0(VH) do {                                                           \
        int s_ = (k0l >> 2) + (VH) * 2;                                        \
        if (ISBF) {                                                            \
            const u16* a0_ = (const u16*)&upa;                                 \
            const u16* a1_ = (const u16*)&upb;                                 \
            _Pragma("unroll")                                                  \
            for (int j = 0; j < 8; ++j) {                                      \
                int e_ = eoV + j;                                              \
                int sl_ = s_ ^ ((e_ + (e_ >> 3)) & 3);                         \
                *(u32*)&ldsV[e_ * 32 + sl_ * 8 + ((2 * k0l) & 7)] =            \
                    (u32)a0_[j] | ((u32)a1_[j] << 16);                         \
            }                                                                  \
        } else {                                                               \
            float t0_[8] = {fpa.x, fpa.y, fpa.z, fpa.w, fpb.x, fpb.y, fpb.z, fpb.w};\
            float t1_[8] = {fpc.x, fpc.y, fpc.z, fpc.w, fpd.x, fpd.y, fpd.z, fpd.w};\
            _Pragma("unroll")                                                  \
            for (int j = 0; j < 8; ++j) {                                      \
                int e_ = eoV + j;                                              \
                int sl_ = s_ ^ ((e_ + (e_ >> 3)) & 3);                         \
                *(u32*)&ldsV[e_ * 32 + sl_ * 8 + ((2 * k0l) & 7)] =            \
                    pkbf(t0_[j], t1_[j]);                                      \
            }                                                                  \
        }                                                                      \
    } while (0)

    // ---------------- compute macros ----------------
#define QK_(ST) do {                                                           \
        (ST) = zv16();                                                         \
        __builtin_amdgcn_s_setprio(1);                                         \
        _Pragma("unroll")                                                      \
        for (int c = 0; c < 4; ++c) {                                          \
            int sl = (2 * c + hi) ^ (l31 & 7);                                 \
            short8 kf = *(const short8*)&ldsK[l31 * 64 + sl * 8];              \
            (ST) = MFMA32(kf, qf[c], (ST));                                    \
        }                                                                      \
        __builtin_amdgcn_s_setprio(0);                                         \
    } while (0)

    u32 c8[8];
#define SM_(SP) do {                                                           \
        _Pragma("unroll")                                                      \
        for (int r = 0; r < 16; ++r) (SP)[r] = fexp2((SP)[r]);                 \
        _Pragma("unroll")                                                      \
        for (int r = 0; r < 16; ++r) psum += (SP)[r];                          \
        _Pragma("unroll")                                                      \
        for (int q = 0; q < 8; ++q) c8[q] = pkbf((SP)[2 * q], (SP)[2 * q + 1]);\
    } while (0)

#define PV_(T) do {                                                            \
        u32 a0 = c8[4 * (T) + 0], a1 = c8[4 * (T) + 1];                        \
        u32 a2 = c8[4 * (T) + 2], a3 = c8[4 * (T) + 3];                        \
        plswap(a0, a2);                                                        \
        plswap(a1, a3);                                                        \
        u32 pw_[4] = { a0, a1, a2, a3 };                                       \
        short8 pa = *(short8*)pw_;                                             \
        __builtin_amdgcn_s_setprio(1);                                         \
        _Pragma("unroll")                                                      \
        for (int et = 0; et < 2; ++et) {                                       \
            int e  = et * 32 + l31;                                            \
            int sl = (2 * (T) + hi) ^ ((e + (e >> 3)) & 3);                    \
            short8 vf = *(const short8*)&ldsV[e * 32 + sl * 8];                \
            O[et] = MFMA32(pa, vf, O[et]);                                     \
        }                                                                      \
        __builtin_amdgcn_s_setprio(0);                                         \
    } while (0)

    // att[2] steady-state body: QK(KT)->SC || SM(SP = tile KT-1 scores);
    // then PV(tile KT-1). gll windows: K(KT+1) lands under PV + next A;
    // V(KT) lands under next region A.
#define BODY(KT, SC, SP) do {                                                  \
        WAITV4();              /* K(KT) landed; V(KT-1) still in flight */     \
        QK_(SC);               /* region A: MFMA/LDS stream             */     \
        SM_(SP);               /*           + independent VALU stream   */     \
        WAITL0();              /* QK ds_reads retired (SM has no ds)    */     \
        GLLK((KT) + 1);                                                        \
        WAITV4();              /* V(KT-1) landed; K(KT+1) stays out     */     \
        PV_(0);                                                                \
        PV_(1);                /* region B: tile KT-1                   */     \
        WAITL0();              /* PV ds_reads retired                   */     \
        GLLV(KT);                                                              \
    } while (0)

    // ---------------- barrier-free K-loop ----------------
    if (WS) {
        // prologue: tile 0 into ldsK; FIFO at BODY(1) top = [K1, V0]
        GLLK(0);
        WAITV0();
        QK_(StA);              // scores of tile 0
        WAITL0();
        GLLK(1);
        GLLV(0);
        // kt = 1..30: odd -> SC=StB, even -> SC=StA
        for (int j = 0; j < 15; ++j) {
            const int kt = 2 * j + 1;
            BODY(kt,     StB, StA);
            BODY(kt + 1, StA, StB);
        }
        // kt = 31 (no GLLK(32))
        WAITV4();              // K31 landed
        QK_(StB);
        SM_(StA);              // tile 30 scores
        WAITL0();
        WAITV0();              // V30 landed
        PV_(0);
        PV_(1);                // tile 30
        WAITL0();
        GLLV(31);
        WAITV0();              // V31 landed
        SM_(StB);              // tile 31
        PV_(0);
        PV_(1);
    } else {
        LK0(0, 0); SK0(0); LK0(0, 1); SK0(1);
        LV0(0, 0); SV0(0); LV0(0, 1); SV0(1);
        for (int kt = 0; kt < 32; ++kt) {
            if (kt < 31) LK0(kt + 1, 0);
            QK_(StA);
            if (kt < 31) { SK0(0); LK0(kt + 1, 1); }
            SM_(StA);
            if (kt < 31) { SK0(1); LV0(kt + 1, 0); }
            PV_(0);
            if (kt < 31) { SV0(0); LV0(kt + 1, 1); }
            PV_(1);
            if (kt < 31) SV0(1);
        }
    }
#undef GLLK
#undef GLLV
#undef WAITV4
#undef WAITV0
#undef WAITL0
#undef LK0
#undef SK0
#undef LV0
#undef SV0
#undef QK_
#undef SM_
#undef PV_
#undef BODY

    // ---- combine the two key-halves through LDS (exact, unnormalized) ----
    __syncthreads();                              // all waves done with tiles
    float pst = psum + __shfl_xor(psum, 32);      // row sum over this half
    float* cb = (float*)SMEM;                     // tiles dead; reuse as f32
    const int cbase = qg * 2368 + lane * 36;      // 36 f32 stride: 16B-aligned

    if (g == 1) {
        union { f32x16 v; float4 q4[4]; } u;
        u.v = O[0];
#pragma unroll
        for (int i = 0; i < 4; ++i) *(float4*)&cb[cbase + 4 * i] = u.q4[i];
        u.v = O[1];
#pragma unroll
        for (int i = 0; i < 4; ++i) *(float4*)&cb[cbase + 16 + 4 * i] = u.q4[i];
        cb[qg * 2368 + 2304 + lane] = pst;
    }

    // ---- l=0 local attention (wave 0 = qg0/g0 of rb==0 blocks) ----
    float locv[2] = {0.f, 0.f};
    float wgt = 0.f;
    const bool w0blk = (rb == 0) && (w == 0);
    if (w0blk) {
        const int e = lane;
        const size_t base = bhoff + e;
#define LDIN(p, i) (ISBF ? bf2f(((const u16*)(p))[i]) : ((const float*)(p))[i])
        float qe = LDIN(qv, base);
        float s[9];
#pragma unroll
        for (int j = 0; j < 9; ++j) {
            float prod = qe * LDIN(kv, base + (size_t)j * HE);
#pragma unroll
            for (int o = 1; o < 64; o <<= 1) prod += __shfl_xor(prod, o);
            s[j] = prod * 0.125f;
        }
        float mx = s[0];
#pragma unroll
        for (int j = 1; j < 9; ++j) mx = fmaxf(mx, s[j]);
        float we[9];
#pragma unroll
        for (int j = 0; j < 9; ++j) we[j] = expf(s[j] - mx);
        float denom = 9.f * we[0];
        float acc   = 9.f * we[0] * LDIN(vv, base);
#pragma unroll
        for (int j = 1; j < 9; ++j) {
            denom += we[j];
            acc   += we[j] * LDIN(vv, base + (size_t)j * HE);
        }
        float loc = acc / denom;

        float a;
        if (ISBF) {
            a = bf2f(((const u16*)alphav)[0]);
            if (!(a >= 0.0f && a <= 1.0f)) {
                float af = ((const float*)alphav)[0];
                if (af >= 0.0f && af <= 1.0f) a = af;
            }
        } else {
            a = ((const float*)alphav)[0];
            if (!(a >= 0.0f && a <= 1.0f)) {
                float ab = bf2f(((const u16*)alphav)[0]);
                if (ab >= 0.0f && ab <= 1.0f) a = ab;
            }
        }
        wgt = 1.f / (1.f + expf(-a));
#pragma unroll
        for (int et = 0; et < 2; ++et) locv[et] = __shfl(loc, et * 32 + l31);
#undef LDIN
    }

    __syncthreads();                              // partials visible
    if (g != 0) return;

    // ---- g==0 waves: add partner partials, normalize, blend, store ----
    float pstp = cb[qg * 2368 + 2304 + lane];
#pragma unroll
    for (int r = 0; r < 16; ++r) {
        O[0][r] += cb[cbase + r];
        O[1][r] += cb[cbase + 16 + r];
    }
    float invv = 1.0f / (pst + pstp);

#pragma unroll
    for (int rg = 0; rg < 4; ++rg) {
#pragma unroll
        for (int rr = 0; rr < 4; ++rr) {
            const int reg = rg * 4 + rr;
            const int rl  = rr + 8 * rg + 4 * hi;       // local output row
            float inv = __shfl(invv, rl);               // broadcast from lane rl
            int row = row0 + qg * 32 + rl;
            size_t oo = (size_t)(b * Lv + row) * HE + h * Ev + l31;
            bool blend = w0blk && (rl == 0);
#pragma unroll
            for (int et = 0; et < 2; ++et) {
                float res = O[et][reg] * inv;
                if (blend) res = wgt * res + (1.f - wgt) * locv[et];
                if (ISBF) ((u16*)outv)[oo + et * 32] = f2bf(res);
                else      ((float*)outv)[oo + et * 32] = res;
            }
        }
    }
}

__global__ __launch_bounds__(512, 4) void attn_kernel_ws(
    const void* __restrict__ qv, const void* __restrict__ kv,
    const void* __restrict__ vv, const void* __restrict__ alphav,
    void* __restrict__ outv, const u16* __restrict__ ws)
{
    // 64 KB: 8 waves x (K tile 4 KB + V tile 4 KB), wave-private.
    // Reused as float scratch (9472 f32) for split-K combine at the end.
    __shared__ u16 SMEM[32768];
    const int isbf = detect_isbf16((const u32*)qv, threadIdx.x & 63);
    if (isbf) attn_impl<1, 1>(qv, kv, vv, alphav, outv, ws, SMEM);
    else      attn_impl<0, 1>(qv, kv, vv, alphav, outv, ws, SMEM);
}

__global__ __launch_bounds__(512, 4) void attn_kernel_nws(
    const void* __restrict__ qv, const void* __restrict__ kv,
    const void* __restrict__ vv, const void* __restrict__ alphav,
    void* __restrict__ outv)
{
    __shared__ u16 SMEM[32768];
    const int isbf = detect_isbf16((const u32*)qv, threadIdx.x & 63);
    if (isbf) attn_impl<1, 0>(qv, kv, vv, alphav, outv, nullptr, SMEM);
    else      attn_impl<0, 0>(qv, kv, vv, alphav, outv, nullptr, SMEM);
}

extern "C" void kernel_launch(void* const* d_in, const int* in_sizes, int n_in,
                              void* d_out, int out_size, void* d_ws, size_t ws_size,
                              hipStream_t stream) {
    if (d_ws != nullptr && ws_size >= WS_NEED) {
        hipLaunchKernelGGL(convert_kernel, dim3(2048), dim3(256), 0, stream,
                           d_in[0], d_in[1], d_in[2], (u16*)d_ws);
        hipLaunchKernelGGL(attn_kernel_ws, dim3(512), dim3(512), 0, stream,
                           d_in[0], d_in[1], d_in[2], d_in[3], d_out,
                           (const u16*)d_ws);
    } else {
        hipLaunchKernelGGL(attn_kernel_nws, dim3(512), dim3(512), 0, stream,
                           d_in[0], d_in[1], d_in[2], d_in[3], d_out);
    }
}

// Round 13
// 146.547 us; speedup vs baseline: 1.0604x; 1.0029x over previous
//
#include <hip/hip_runtime.h>

typedef unsigned short u16;
typedef unsigned int   u32;
typedef __attribute__((ext_vector_type(8))) short short8;   // 8 x bf16 (4 VGPRs)
typedef __attribute__((ext_vector_type(16))) float f32x16;

#define MFMA32(a, b, c) __builtin_amdgcn_mfma_f32_32x32x16_bf16(a, b, c, 0, 0, 0)

constexpr int Lv = 2048, Hv = 8, Ev = 64, HE = Hv * Ev; // HE=512
constexpr float QSCALE = 0.18033688011112042f;          // 0.125 * log2(e)
constexpr size_t WSV_OFF = 32u * 64u * 2048u;           // u16 offset of V images
#define WS_NEED ((size_t)16777216)

__device__ __forceinline__ float bf2f(u16 u) {
    u32 x = ((u32)u) << 16;
    return __builtin_bit_cast(float, x);
}
__device__ __forceinline__ u16 f2bf(float f) {   // RNE, finite inputs
    u32 x = __builtin_bit_cast(u32, f);
    u32 r = ((x >> 16) & 1u) + 0x7fffu;
    return (u16)((x + r) >> 16);
}
__device__ __forceinline__ u32 pkbf(float a, float b) {
#if __has_builtin(__builtin_amdgcn_cvt_pk_bf16_f32)
    typedef __attribute__((ext_vector_type(2))) __bf16 bf16x2;
    bf16x2 v = __builtin_amdgcn_cvt_pk_bf16_f32(a, b);
    return __builtin_bit_cast(u32, v);
#else
    return (u32)f2bf(a) | ((u32)f2bf(b) << 16);
#endif
}
__device__ __forceinline__ float fexp2(float x) {
#if __has_builtin(__builtin_amdgcn_exp2f)
    return __builtin_amdgcn_exp2f(x);
#else
    return exp2f(x);
#endif
}

// async global(16B/lane) -> LDS(base + lane*16). Guide §5 / m97 pattern.
__device__ __forceinline__ void gll16(const void* g, void* l) {
    __builtin_amdgcn_global_load_lds(
        (const __attribute__((address_space(1))) void*)g,
        (__attribute__((address_space(3))) void*)l, 16, 0, 0);
}

// Runtime dtype sniff (validated rounds 0-12: fp32 inputs detected correctly).
__device__ __forceinline__ int detect_isbf16(const u32* q32, int lane) {
    u32 w0 = q32[2 * lane];
    u32 w1 = q32[2 * lane + 1];
    u16 uu[4] = { (u16)(w0 & 0xffff), (u16)(w0 >> 16),
                  (u16)(w1 & 0xffff), (u16)(w1 >> 16) };
    int p = 0, z = 0;
#pragma unroll
    for (int j = 0; j < 4; ++j) {
        u16 mgn = (u16)(uu[j] & 0x7fff);
        int ex  = mgn >> 7;
        bool zero = (mgn == 0);
        bool pl   = zero || (ex >= 115 && ex <= 132);
        p += pl ? 1 : 0;
        if ((j & 1) == 0) z += zero ? 1 : 0;
    }
    int acc = p | (z << 16);
#pragma unroll
    for (int o = 1; o < 64; o <<= 1) acc += __shfl_xor(acc, o);
    int ps = acc & 0xffff, zs = acc >> 16;
    if (zs >= 100) return 0;
    return (ps >= 240) ? 1 : 0;
}

__device__ __forceinline__ short8 cvt8s(const float* p, float s) {
    float4 a = *(const float4*)p, b4 = *(const float4*)(p + 4);
    u32 r[4] = { pkbf(a.x * s, a.y * s), pkbf(a.z * s, a.w * s),
                 pkbf(b4.x * s, b4.y * s), pkbf(b4.z * s, b4.w * s) };
    return *(short8*)r;
}

__device__ __forceinline__ f32x16 zv16() {
    f32x16 z;
#pragma unroll
    for (int r = 0; r < 16; ++r) z[r] = 0.f;
    return z;
}

// Exchange a.hi-lanes <-> b.lo-lanes (v_permlane32_swap_b32 semantics).
__device__ __forceinline__ void plswap(u32& a, u32& b) {
#if __has_builtin(__builtin_amdgcn_permlane32_swap)
    auto r = __builtin_amdgcn_permlane32_swap(a, b, false, false);
    a = r[0]; b = r[1];
#else
    int lane = (int)(threadIdx.x & 63);
    u32 ax = (u32)__shfl_xor((int)a, 32);
    u32 bx = (u32)__shfl_xor((int)b, 32);
    bool hi = lane >= 32;
    u32 na = hi ? bx : a;
    u32 nb = hi ? b  : ax;
    a = na; b = nb;
#endif
}

// ---------------------------------------------------------------------------
// Convert kernel (round-13): same image layout as rounds 10-12 (attn reader
// unchanged), rebuilt for width + XCD locality:
//   * K phase: 32B reads / 16B writes per lane (was 8B/4B).
//   * V image phase: uint2 writes (was u32); VT stride 68 -> 72 u16 so all
//     LDS stores are 8/16B-aligned.
//   * Block mapping XCD-ALIGNED to the attn consumer: attn block fid has
//     xcd = fid&7 and reads bh = (fid&7)*4 + ((fid>>3)&3); convert now maps
//     blk -> (xcd = blk&7, bh = xcd*4 + ((blk>>3)&3), tg = blk>>5) so the
//     images are produced in the same XCD L2 that consumes them.
// K image:  addr a: key=a>>6, sf=(a&63)>>3, j=a&7, e=((sf^(key&7))<<3)+j
// V image:  addr a: e=a>>5,  sf=(a&31)>>3, j=a&7, key=((sf^((e+(e>>3))&3))<<3)+j
// ---------------------------------------------------------------------------
template <int ISBF>
__device__ __forceinline__ void convert_impl(const void* kin, const void* vin,
                                             u16* __restrict__ ws, u16* VT) {
    const int blk = blockIdx.x;            // 0..2047
    const int xcd = blk & 7;
    const int bh  = xcd * 4 + ((blk >> 3) & 3);
    const int tg  = blk >> 5;              // 0..63
    const int b   = bh >> 3, h = bh & 7;
    const size_t inb = (size_t)b * Lv * HE + h * Ev;
    u16* kimg = ws + ((size_t)bh * 64 + tg) * 2048;
    u16* vimg = ws + WSV_OFF + ((size_t)bh * 64 + tg) * 2048;
    const int t = threadIdx.x;             // 0..255

    // ---- Phase 1: V rows -> VT[key*72 + e] (bf16), coalesced wide reads ----
    if (ISBF) {
        // one iter: 16B read + 16B LDS write per lane
        int key = t >> 3, p8 = t & 7;
        size_t src = inb + (size_t)(tg * 32 + key) * HE + p8 * 8;
        uint4 v = *(const uint4*)((const u16*)vin + src);
        *(uint4*)&VT[key * 72 + p8 * 8] = v;
    } else {
#pragma unroll
        for (int r = 0; r < 2; ++r) {
            int f = t + 256 * r;           // 0..511
            int key = f >> 4, part = f & 15;
            size_t src = inb + (size_t)(tg * 32 + key) * HE + part * 4;
            float4 v = *(const float4*)((const float*)vin + src);
            uint2 pv; pv.x = pkbf(v.x, v.y); pv.y = pkbf(v.z, v.w);
            *(uint2*)&VT[key * 72 + part * 4] = pv;
        }
    }

    // ---- K image: direct, wide (overlaps V load latency; no LDS dep) ----
    {
        int a = 8 * t;                     // u16 addr, 0..2040 step 8
        int key = a >> 6, sf = (a & 63) >> 3;
        int e0 = ((sf ^ (key & 7)) << 3);
        size_t s = inb + (size_t)(tg * 32 + key) * HE + e0;
        if (ISBF) {
            uint4 v = *(const uint4*)((const u16*)kin + s);
            *(uint4*)&kimg[a] = v;
        } else {
            float4 p0 = *(const float4*)((const float*)kin + s);
            float4 p1 = *(const float4*)((const float*)kin + s + 4);
            uint4 v; v.x = pkbf(p0.x, p0.y); v.y = pkbf(p0.z, p0.w);
                     v.z = pkbf(p1.x, p1.y); v.w = pkbf(p1.z, p1.w);
            *(uint4*)&kimg[a] = v;
        }
    }

    __syncthreads();

    // ---- Phase 2: V image, 8B coalesced writes; LDS absorbs the scatter ----
#pragma unroll
    for (int r = 0; r < 2; ++r) {
        int idx = t + 256 * r;             // 0..511
        int a = 4 * idx;                   // u16 addr, step 4
        int e = a >> 5, sf = (a & 31) >> 3, j0 = a & 7;   // j0 in {0,4}
        int m = (e + (e >> 3)) & 3;
        int k0 = ((sf ^ m) << 3) + j0;     // keys k0..k0+3 at this e
        uint2 val;
        val.x = (u32)VT[k0 * 72 + e]       | ((u32)VT[(k0 + 1) * 72 + e] << 16);
        val.y = (u32)VT[(k0 + 2) * 72 + e] | ((u32)VT[(k0 + 3) * 72 + e] << 16);
        *(uint2*)&vimg[a] = val;
    }
}

__global__ __launch_bounds__(256) void convert_kernel(
    const void* __restrict__ qv, const void* __restrict__ kv,
    const void* __restrict__ vv, u16* __restrict__ ws)
{
    __shared__ u16 VT[32 * 72];            // 4.5 KB transpose tile
    const int isbf = detect_isbf16((const u32*)qv, threadIdx.x & 63);
    if (isbf) convert_impl<1>(kv, vv, ws, VT);
    else      convert_impl<0>(kv, vv, ws, VT);
}

// ---------------------------------------------------------------------------
// Fused full attention + l=0 local blend.  Round-13 attn = round-12 attn,
// BYTE-IDENTICAL (proven 63.7 us, WRITE=output, VGPR 64 + 64 AGPR = exactly
// the 128/wave budget — any added per-wave state spills, so attn is frozen
// this round; the convert kernel is the optimization target).
// Barrier-free K-loop, wave-private 8 KB LDS, gll staging from pre-swizzled
// images, att[2] (QK(kt) || SM(kt-1)), counted vmcnt, split-K combine.
// WS=0 fallback: round-10 direct-staging path, unchanged.
// ---------------------------------------------------------------------------
template <int ISBF, int WS>
__device__ __forceinline__ void attn_impl(
    const void* __restrict__ qv, const void* __restrict__ kv,
    const void* __restrict__ vv, const void* __restrict__ alphav,
    void* __restrict__ outv, const u16* __restrict__ ws, u16* SMEM)
{
    const int tid  = threadIdx.x;       // 0..511
    const int w    = tid >> 6;          // wave 0..7
    const int lane = tid & 63;
    const int l31  = lane & 31;
    const int hi   = lane >> 5;
    const int qg   = w & 3;             // query sub-block (32 rows)
    const int g    = w >> 2;            // key-half group (1024 keys)

    // XCD-aware mapping: xcd = fid&7 handles bh in {4*xcd .. 4*xcd+3}.
    const int fid = blockIdx.x;         // 0..511
    const int bh  = (fid & 7) * 4 + ((fid >> 3) & 3);
    const int rb  = fid >> 5;           // 0..15
    const int b   = bh >> 3, h = bh & 7;
    const int row0 = rb * 128;

    const size_t bhoff = (size_t)b * Lv * HE + h * Ev;
    const u16*   q16 = (const u16*)qv + bhoff;
    const u16*   k16 = (const u16*)kv + bhoff;
    const u16*   v16 = (const u16*)vv + bhoff;
    const float* q32 = (const float*)qv + bhoff;
    const float* k32 = (const float*)kv + bhoff;
    const float* v32 = (const float*)vv + bhoff;

    // wave-private LDS slice: K tile [32 key][64 e] + V tile [64 e][32 key]
    u16* ldsK = SMEM + w * 4096;
    u16* ldsV = ldsK + 2048;

    // Q fragments (pre-scaled). qf[c][j] = Qs[row0+qg*32+l31][16c+8hi+j].
    short8 qf[4];
    {
        size_t ro = (size_t)(row0 + qg * 32 + l31) * HE + hi * 8;
        if (ISBF) {
#pragma unroll
            for (int c = 0; c < 4; ++c) {
                short8 t = *(const short8*)(q16 + ro + 16 * c);
#pragma unroll
                for (int j = 0; j < 8; ++j)
                    qf[c][j] = (short)f2bf(bf2f((u16)t[j]) * QSCALE);
            }
        } else {
#pragma unroll
            for (int c = 0; c < 4; ++c) qf[c] = cvt8s(q32 + ro + 16 * c, QSCALE);
        }
    }

    f32x16 O[2];
    O[0] = zv16(); O[1] = zv16();
    f32x16 StA = zv16(), StB = zv16();   // att[2] ping-pong score states
    float psum = 0.f;

    // image bases (WS=1): tile tg = g*32 + kt
    const u16* kimg0 = ws + ((size_t)bh * 64 + g * 32) * 2048;
    const u16* vimg0 = ws + WSV_OFF + ((size_t)bh * 64 + g * 32) * 2048;
    const size_t keybase = (size_t)g * 1024;     // WS=0 global key offset

    // WS=0 staging lane mapping
    const int k0l = lane >> 3;
    const int kj  = lane & 7;
    const int e0K = ((kj ^ k0l) << 3);
    const int eoV = kj * 8;

    // WS=0 prefetch registers
    float4 fpa, fpb, fpc, fpd;
    uint4  upa, upb;

    // ---------------- WS=1 gll staging ----------------
#define GLLK(KT) do {                                                          \
        const u16* ib_ = kimg0 + (size_t)(KT) * 2048 + lane * 8;               \
        _Pragma("unroll")                                                      \
        for (int s_ = 0; s_ < 4; ++s_)                                         \
            gll16(ib_ + s_ * 512, ldsK + s_ * 512);                            \
    } while (0)
#define GLLV(KT) do {                                                          \
        const u16* ib_ = vimg0 + (size_t)(KT) * 2048 + lane * 8;               \
        _Pragma("unroll")                                                      \
        for (int s_ = 0; s_ < 4; ++s_)                                         \
            gll16(ib_ + s_ * 512, ldsV + s_ * 512);                            \
    } while (0)
#define WAITV4() do { asm volatile("s_waitcnt vmcnt(4)" ::: "memory");         \
        __builtin_amdgcn_sched_barrier(0); } while (0)
#define WAITV0() do { asm volatile("s_waitcnt vmcnt(0)" ::: "memory");         \
        __builtin_amdgcn_sched_barrier(0); } while (0)
#define WAITL0() do { asm volatile("s_waitcnt lgkmcnt(0)" ::: "memory");       \
        __builtin_amdgcn_sched_barrier(0); } while (0)

    // ---------------- WS=0 staging (round-10, unchanged) ----------------
#define LK0(KT, CH) do {                                                       \
        size_t tb_ = (keybase + (size_t)(KT) * 32) * HE;                       \
        int key_ = (CH) * 16 + k0l;                                            \
        if (ISBF) {                                                            \
            const u16* p_ = k16 + tb_ + (size_t)key_ * HE + e0K;               \
            upa = *(const uint4*)p_;                                           \
            upb = *(const uint4*)(p_ + 8 * HE);                                \
        } else {                                                               \
            const float* p_ = k32 + tb_ + (size_t)key_ * HE + e0K;             \
            fpa = *(const float4*)p_;            fpb = *(const float4*)(p_ + 4);\
            fpc = *(const float4*)(p_ + 8 * HE); fpd = *(const float4*)(p_ + 8 * HE + 4);\
        }                                                                      \
    } while (0)
#define SK0(CH) do {                                                           \
        if (ISBF) {                                                            \
            *(uint4*)&ldsK[((CH)*2    ) * 512 + lane * 8] = upa;               \
            *(uint4*)&ldsK[((CH)*2 + 1) * 512 + lane * 8] = upb;               \
        } else {                                                               \
            u32 t0_[4] = { pkbf(fpa.x, fpa.y), pkbf(fpa.z, fpa.w),             \
                           pkbf(fpb.x, fpb.y), pkbf(fpb.z, fpb.w) };           \
            u32 t1_[4] = { pkbf(fpc.x, fpc.y), pkbf(fpc.z, fpc.w),             \
                           pkbf(fpd.x, fpd.y), pkbf(fpd.z, fpd.w) };           \
            *(uint4*)&ldsK[((CH)*2    ) * 512 + lane * 8] = *(uint4*)t0_;      \
            *(uint4*)&ldsK[((CH)*2 + 1) * 512 + lane * 8] = *(uint4*)t1_;      \
        }                                                                      \
    } while (0)
#define LV0(KT, VH) do {                                                       \
        size_t tb_ = (keybase + (size_t)(KT) * 32 + (VH) * 16 + 2 * k0l) * HE; \
        if (ISBF) {                                                            \
            const u16* p_ = v16 + tb_ + eoV;                                   \
            upa = *(const uint4*)p_;                                           \
            upb = *(const uint4*)(p_ + HE);                                    \
        } else {                                                               \
            const float* p_ = v32 + tb_ + eoV;                                 \
            fpa = *(const float4*)p_;       fpb = *(const float4*)(p_ + 4);    \
            fpc = *(const float4*)(p_ + HE); fpd = *(const float4*)(p_ + HE + 4);\
        }                                                                      \
    } while (0)
#define SV0(VH) do {                                                           \
        int s_ = (k0l >> 2) + (VH) * 2;                                        \
        if (ISBF) {                                                            \
            const u16* a0_ = (const u16*)&upa;                                 \
            const u16* a1_ = (const u16*)&upb;                                 \
            _Pragma("unroll")                                                  \
            for (int j = 0; j < 8; ++j) {                                      \
                int e_ = eoV + j;                                              \
                int sl_ = s_ ^ ((e_ + (e_ >> 3)) & 3);                         \
                *(u32*)&ldsV[e_ * 32 + sl_ * 8 + ((2 * k0l) & 7)] =            \
                    (u32)a0_[j] | ((u32)a1_[j] << 16);                         \
            }                                                                  \
        } else {                                                               \
            float t0_[8] = {fpa.x, fpa.y, fpa.z, fpa.w, fpb.x, fpb.y, fpb.z, fpb.w};\
            float t1_[8] = {fpc.x, fpc.y, fpc.z, fpc.w, fpd.x, fpd.y, fpd.z, fpd.w};\
            _Pragma("unroll")                                                  \
            for (int j = 0; j < 8; ++j) {                                      \
                int e_ = eoV + j;                                              \
                int sl_ = s_ ^ ((e_ + (e_ >> 3)) & 3);                         \
                *(u32*)&ldsV[e_ * 32 + sl_ * 8 + ((2 * k0l) & 7)] =            \
                    pkbf(t0_[j], t1_[j]);                                      \
            }                                                                  \
        }                                                                      \
    } while (0)

    // ---------------- compute macros ----------------
#define QK_(ST) do {                                                           \
        (ST) = zv16();                                                         \
        __builtin_amdgcn_s_setprio(1);                                         \
        _Pragma("unroll")                                                      \
        for (int c = 0; c < 4; ++c) {                                          \
            int sl = (2 * c + hi) ^ (l31 & 7);                                 \
            short8 kf = *(const short8*)&ldsK[l31 * 64 + sl * 8];              \
            (ST) = MFMA32(kf, qf[c], (ST));                                    \
        }                                                                      \
        __builtin_amdgcn_s_setprio(0);                                         \
    } while (0)

    u32 c8[8];
#define SM_(SP) do {                                                           \
        _Pragma("unroll")                                                      \
        for (int r = 0; r < 16; ++r) (SP)[r] = fexp2((SP)[r]);                 \
        _Pragma("unroll")                                                      \
        for (int r = 0; r < 16; ++r) psum += (SP)[r];                          \
        _Pragma("unroll")                                                      \
        for (int q = 0; q < 8; ++q) c8[q] = pkbf((SP)[2 * q], (SP)[2 * q + 1]);\
    } while (0)

#define PV_(T) do {                                                            \
        u32 a0 = c8[4 * (T) + 0], a1 = c8[4 * (T) + 1];                        \
        u32 a2 = c8[4 * (T) + 2], a3 = c8[4 * (T) + 3];                        \
        plswap(a0, a2);                                                        \
        plswap(a1, a3);                                                        \
        u32 pw_[4] = { a0, a1, a2, a3 };                                       \
        short8 pa = *(short8*)pw_;                                             \
        __builtin_amdgcn_s_setprio(1);                                         \
        _Pragma("unroll")                                                      \
        for (int et = 0; et < 2; ++et) {                                       \
            int e  = et * 32 + l31;                                            \
            int sl = (2 * (T) + hi) ^ ((e + (e >> 3)) & 3);                    \
            short8 vf = *(const short8*)&ldsV[e * 32 + sl * 8];                \
            O[et] = MFMA32(pa, vf, O[et]);                                     \
        }                                                                      \
        __builtin_amdgcn_s_setprio(0);                                         \
    } while (0)

    // att[2] steady-state body: QK(KT)->SC || SM(SP = tile KT-1 scores);
    // then PV(tile KT-1). gll windows: K(KT+1) lands under PV + next A;
    // V(KT) lands under next region A.
#define BODY(KT, SC, SP) do {                                                  \
        WAITV4();              /* K(KT) landed; V(KT-1) still in flight */     \
        QK_(SC);               /* region A: MFMA/LDS stream             */     \
        SM_(SP);               /*           + independent VALU stream   */     \
        WAITL0();              /* QK ds_reads retired (SM has no ds)    */     \
        GLLK((KT) + 1);                                                        \
        WAITV4();              /* V(KT-1) landed; K(KT+1) stays out     */     \
        PV_(0);                                                                \
        PV_(1);                /* region B: tile KT-1                   */     \
        WAITL0();              /* PV ds_reads retired                   */     \
        GLLV(KT);                                                              \
    } while (0)

    // ---------------- barrier-free K-loop ----------------
    if (WS) {
        // prologue: tile 0 into ldsK; FIFO at BODY(1) top = [K1, V0]
        GLLK(0);
        WAITV0();
        QK_(StA);              // scores of tile 0
        WAITL0();
        GLLK(1);
        GLLV(0);
        // kt = 1..30: odd -> SC=StB, even -> SC=StA
        for (int j = 0; j < 15; ++j) {
            const int kt = 2 * j + 1;
            BODY(kt,     StB, StA);
            BODY(kt + 1, StA, StB);
        }
        // kt = 31 (no GLLK(32))
        WAITV4();              // K31 landed
        QK_(StB);
        SM_(StA);              // tile 30 scores
        WAITL0();
        WAITV0();              // V30 landed
        PV_(0);
        PV_(1);                // tile 30
        WAITL0();
        GLLV(31);
        WAITV0();              // V31 landed
        SM_(StB);              // tile 31
        PV_(0);
        PV_(1);
    } else {
        LK0(0, 0); SK0(0); LK0(0, 1); SK0(1);
        LV0(0, 0); SV0(0); LV0(0, 1); SV0(1);
        for (int kt = 0; kt < 32; ++kt) {
            if (kt < 31) LK0(kt + 1, 0);
            QK_(StA);
            if (kt < 31) { SK0(0); LK0(kt + 1, 1); }
            SM_(StA);
            if (kt < 31) { SK0(1); LV0(kt + 1, 0); }
            PV_(0);
            if (kt < 31) { SV0(0); LV0(kt + 1, 1); }
            PV_(1);
            if (kt < 31) SV0(1);
        }
    }
#undef GLLK
#undef GLLV
#undef WAITV4
#undef WAITV0
#undef WAITL0
#undef LK0
#undef SK0
#undef LV0
#undef SV0
#undef QK_
#undef SM_
#undef PV_
#undef BODY

    // ---- combine the two key-halves through LDS (exact, unnormalized) ----
    __syncthreads();                              // all waves done with tiles
    float pst = psum + __shfl_xor(psum, 32);      // row sum over this half
    float* cb = (float*)SMEM;                     // tiles dead; reuse as f32
    const int cbase = qg * 2368 + lane * 36;      // 36 f32 stride: 16B-aligned

    if (g == 1) {
        union { f32x16 v; float4 q4[4]; } u;
        u.v = O[0];
#pragma unroll
        for (int i = 0; i < 4; ++i) *(float4*)&cb[cbase + 4 * i] = u.q4[i];
        u.v = O[1];
#pragma unroll
        for (int i = 0; i < 4; ++i) *(float4*)&cb[cbase + 16 + 4 * i] = u.q4[i];
        cb[qg * 2368 + 2304 + lane] = pst;
    }

    // ---- l=0 local attention (wave 0 = qg0/g0 of rb==0 blocks) ----
    float locv[2] = {0.f, 0.f};
    float wgt = 0.f;
    const bool w0blk = (rb == 0) && (w == 0);
    if (w0blk) {
        const int e = lane;
        const size_t base = bhoff + e;
#define LDIN(p, i) (ISBF ? bf2f(((const u16*)(p))[i]) : ((const float*)(p))[i])
        float qe = LDIN(qv, base);
        float s[9];
#pragma unroll
        for (int j = 0; j < 9; ++j) {
            float prod = qe * LDIN(kv, base + (size_t)j * HE);
#pragma unroll
            for (int o = 1; o < 64; o <<= 1) prod += __shfl_xor(prod, o);
            s[j] = prod * 0.125f;
        }
        float mx = s[0];
#pragma unroll
        for (int j = 1; j < 9; ++j) mx = fmaxf(mx, s[j]);
        float we[9];
#pragma unroll
        for (int j = 0; j < 9; ++j) we[j] = expf(s[j] - mx);
        float denom = 9.f * we[0];
        float acc   = 9.f * we[0] * LDIN(vv, base);
#pragma unroll
        for (int j = 1; j < 9; ++j) {
            denom += we[j];
            acc   += we[j] * LDIN(vv, base + (size_t)j * HE);
        }
        float loc = acc / denom;

        float a;
        if (ISBF) {
            a = bf2f(((const u16*)alphav)[0]);
            if (!(a >= 0.0f && a <= 1.0f)) {
                float af = ((const float*)alphav)[0];
                if (af >= 0.0f && af <= 1.0f) a = af;
            }
        } else {
            a = ((const float*)alphav)[0];
            if (!(a >= 0.0f && a <= 1.0f)) {
                float ab = bf2f(((const u16*)alphav)[0]);
                if (ab >= 0.0f && ab <= 1.0f) a = ab;
            }
        }
        wgt = 1.f / (1.f + expf(-a));
#pragma unroll
        for (int et = 0; et < 2; ++et) locv[et] = __shfl(loc, et * 32 + l31);
#undef LDIN
    }

    __syncthreads();                              // partials visible
    if (g != 0) return;

    // ---- g==0 waves: add partner partials, normalize, blend, store ----
    float pstp = cb[qg * 2368 + 2304 + lane];
#pragma unroll
    for (int r = 0; r < 16; ++r) {
        O[0][r] += cb[cbase + r];
        O[1][r] += cb[cbase + 16 + r];
    }
    float invv = 1.0f / (pst + pstp);

#pragma unroll
    for (int rg = 0; rg < 4; ++rg) {
#pragma unroll
        for (int rr = 0; rr < 4; ++rr) {
            const int reg = rg * 4 + rr;
            const int rl  = rr + 8 * rg + 4 * hi;       // local output row
            float inv = __shfl(invv, rl);               // broadcast from lane rl
            int row = row0 + qg * 32 + rl;
            size_t oo = (size_t)(b * Lv + row) * HE + h * Ev + l31;
            bool blend = w0blk && (rl == 0);
#pragma unroll
            for (int et = 0; et < 2; ++et) {
                float res = O[et][reg] * inv;
                if (blend) res = wgt * res + (1.f - wgt) * locv[et];
                if (ISBF) ((u16*)outv)[oo + et * 32] = f2bf(res);
                else      ((float*)outv)[oo + et * 32] = res;
            }
        }
    }
}

__global__ __launch_bounds__(512, 4) void attn_kernel_ws(
    const void* __restrict__ qv, const void* __restrict__ kv,
    const void* __restrict__ vv, const void* __restrict__ alphav,
    void* __restrict__ outv, const u16* __restrict__ ws)
{
    // 64 KB: 8 waves x (K tile 4 KB + V tile 4 KB), wave-private.
    // Reused as float scratch (9472 f32) for split-K combine at the end.
    __shared__ u16 SMEM[32768];
    const int isbf = detect_isbf16((const u32*)qv, threadIdx.x & 63);
    if (isbf) attn_impl<1, 1>(qv, kv, vv, alphav, outv, ws, SMEM);
    else      attn_impl<0, 1>(qv, kv, vv, alphav, outv, ws, SMEM);
}

__global__ __launch_bounds__(512, 4) void attn_kernel_nws(
    const void* __restrict__ qv, const void* __restrict__ kv,
    const void* __restrict__ vv, const void* __restrict__ alphav,
    void* __restrict__ outv)
{
    __shared__ u16 SMEM[32768];
    const int isbf = detect_isbf16((const u32*)qv, threadIdx.x & 63);
    if (isbf) attn_impl<1, 0>(qv, kv, vv, alphav, outv, nullptr, SMEM);
    else      attn_impl<0, 0>(qv, kv, vv, alphav, outv, nullptr, SMEM);
}

extern "C" void kernel_launch(void* const* d_in, const int* in_sizes, int n_in,
                              void* d_out, int out_size, void* d_ws, size_t ws_size,
                              hipStream_t stream) {
    if (d_ws != nullptr && ws_size >= WS_NEED) {
        hipLaunchKernelGGL(convert_kernel, dim3(2048), dim3(256), 0, stream,
                           d_in[0], d_in[1], d_in[2], (u16*)d_ws);
        hipLaunchKernelGGL(attn_kernel_ws, dim3(512), dim3(512), 0, stream,
                           d_in[0], d_in[1], d_in[2], d_in[3], d_out,
                           (const u16*)d_ws);
    } else {
        hipLaunchKernelGGL(attn_kernel_nws, dim3(512), dim3(512), 0, stream,
                           d_in[0], d_in[1], d_in[2], d_in[3], d_out);
    }
}